// Round 1
// baseline (9038.338 us; speedup 1.0000x reference)
//
#include <hip/hip_runtime.h>
#include <math.h>

#define Gd 64
#define G2 4096
#define G3 262144
#define CIN 64
#define HIDC 128
#define NB 2
#define TOPKN 128
#define NCLASS 34
#define CAPN 65536
#define DET_TH 0.2f

// ---------------- weight repack: w[co][ci][27] -> wpk[ci*27+tap][co] -------------
__global__ void repack_k(const float* __restrict__ w, float* __restrict__ wpk, int ci_n){
    int i = blockIdx.x*256 + threadIdx.x;
    int total = HIDC*ci_n*27;
    if (i >= total) return;
    int co = i/(ci_n*27);
    int r  = i - co*(ci_n*27);           // ci*27 + tap
    wpk[(size_t)r*HIDC + co] = w[i];
}

// ---------------- conv1: neck(64ch) -> hidden1(128ch), bias+relu, one z-slab -----
// grid: (y=64, p=nplanes), block 256 = 4 waves, wave w owns co [32w,32w+32)
__global__ void __launch_bounds__(256) conv1_k(
    const float* __restrict__ in,      // batch-offset [CIN][G3]
    const float* __restrict__ wpk,     // [CIN*27][128]
    const float* __restrict__ b1,      // [128]
    float* __restrict__ h1,            // [128][nplanes][G2]
    int z0, int nplanes)
{
    const int y    = blockIdx.x;
    const int p    = blockIdx.y;
    const int z    = z0 - 1 + p;
    const int lane = threadIdx.x & 63;
    const int wv   = __builtin_amdgcn_readfirstlane(threadIdx.x >> 6);
    const int co0  = wv*32;
    const size_t obase = (size_t)p*G2 + (size_t)y*Gd + lane;

    __shared__ float sbuf[2][9][66];

    if (z < 0 || z >= Gd){   // halo plane outside grid: conv2 'SAME' zero-pad
        #pragma unroll
        for (int j=0;j<32;++j) h1[(size_t)(co0+j)*nplanes*G2 + obase] = 0.f;
        return;
    }

    float acc[32];
    #pragma unroll
    for (int j=0;j<32;++j) acc[j] = b1[co0+j];

    // stage ci=0
    for (int e=threadIdx.x; e<9*66; e+=256){
        int row=e/66, col=e-row*66;
        int dz=row/3, dy=row-dz*3;
        int gz=z-1+dz, gy=y-1+dy, gx=col-1;
        float v=0.f;
        if ((unsigned)gz<64u && (unsigned)gy<64u && (unsigned)gx<64u)
            v = in[(size_t)gz*G2 + gy*Gd + gx];
        sbuf[0][row][col]=v;
    }
    __syncthreads();

    for (int ci=0; ci<CIN; ++ci){
        if (ci+1 < CIN){     // prefetch next ci into other buffer
            const float* ip = in + (size_t)(ci+1)*G3;
            int nbuf = (ci+1)&1;
            for (int e=threadIdx.x; e<9*66; e+=256){
                int row=e/66, col=e-row*66;
                int dz=row/3, dy=row-dz*3;
                int gz=z-1+dz, gy=y-1+dy, gx=col-1;
                float v=0.f;
                if ((unsigned)gz<64u && (unsigned)gy<64u && (unsigned)gx<64u)
                    v = ip[(size_t)gz*G2 + gy*Gd + gx];
                sbuf[nbuf][row][col]=v;
            }
        }
        const int bs = ci&1;
        float a[27];
        #pragma unroll
        for (int rr=0; rr<9; ++rr){
            a[rr*3+0]=sbuf[bs][rr][lane+0];
            a[rr*3+1]=sbuf[bs][rr][lane+1];
            a[rr*3+2]=sbuf[bs][rr][lane+2];
        }
        const float* wb = wpk + (size_t)ci*27*HIDC + co0;  // wave-uniform -> s_load
        #pragma unroll
        for (int t=0;t<27;++t){
            const float* wr = wb + t*HIDC;
            #pragma unroll
            for (int j=0;j<32;++j) acc[j] = fmaf(a[t], wr[j], acc[j]);
        }
        __syncthreads();
    }
    #pragma unroll
    for (int j=0;j<32;++j){
        float v = acc[j] > 0.f ? acc[j] : 0.f;
        h1[(size_t)(co0+j)*nplanes*G2 + obase] = v;
    }
}

// ---------------- conv2 fused: hidden1 -> relu -> wf-dot -> sigmoid -> scores ----
__global__ void __launch_bounds__(256) conv2_k(
    const float* __restrict__ h1,      // [128][nplanes][G2]
    const float* __restrict__ wpk,     // [128*27][128]
    const float* __restrict__ b2,      // [128]
    const float* __restrict__ wf,      // [128]
    const float* __restrict__ bf,      // [1]
    float* __restrict__ scores,        // batch-offset [G3]
    int z0, int nplanes)
{
    const int y    = blockIdx.x;
    const int z    = z0 + blockIdx.y;
    const int lane = threadIdx.x & 63;
    const int wv   = __builtin_amdgcn_readfirstlane(threadIdx.x >> 6);
    const int co0  = wv*32;
    const int pb   = z - z0;           // plane index of dz=0 (z-1 plane)

    __shared__ float sbuf[2][9][66];
    __shared__ float red[4][64];

    float acc[32];
    #pragma unroll
    for (int j=0;j<32;++j) acc[j] = b2[co0+j];

    for (int e=threadIdx.x; e<9*66; e+=256){
        int row=e/66, col=e-row*66;
        int dz=row/3, dy=row-dz*3;
        int gy=y-1+dy, gx=col-1;
        float v=0.f;
        if ((unsigned)gy<64u && (unsigned)gx<64u)
            v = h1[(size_t)(pb+dz)*G2 + gy*Gd + gx];
        sbuf[0][row][col]=v;
    }
    __syncthreads();

    for (int ci=0; ci<HIDC; ++ci){
        if (ci+1 < HIDC){
            const float* hp = h1 + (size_t)(ci+1)*nplanes*G2;
            int nbuf=(ci+1)&1;
            for (int e=threadIdx.x; e<9*66; e+=256){
                int row=e/66, col=e-row*66;
                int dz=row/3, dy=row-dz*3;
                int gy=y-1+dy, gx=col-1;
                float v=0.f;
                if ((unsigned)gy<64u && (unsigned)gx<64u)
                    v = hp[(size_t)(pb+dz)*G2 + gy*Gd + gx];
                sbuf[nbuf][row][col]=v;
            }
        }
        const int bs = ci&1;
        float a[27];
        #pragma unroll
        for (int rr=0; rr<9; ++rr){
            a[rr*3+0]=sbuf[bs][rr][lane+0];
            a[rr*3+1]=sbuf[bs][rr][lane+1];
            a[rr*3+2]=sbuf[bs][rr][lane+2];
        }
        const float* wb = wpk + (size_t)ci*27*HIDC + co0;
        #pragma unroll
        for (int t=0;t<27;++t){
            const float* wr = wb + t*HIDC;
            #pragma unroll
            for (int j=0;j<32;++j) acc[j] = fmaf(a[t], wr[j], acc[j]);
        }
        __syncthreads();
    }
    // epilogue: relu, dot with wf, cross-wave reduce, + bf, sigmoid
    float part = 0.f;
    #pragma unroll
    for (int j=0;j<32;++j){
        float v = acc[j] > 0.f ? acc[j] : 0.f;
        part = fmaf(v, wf[co0+j], part);
    }
    red[wv][lane] = part;
    __syncthreads();
    if (wv==0){
        float s = red[0][lane]+red[1][lane]+red[2][lane]+red[3][lane] + bf[0];
        scores[(size_t)z*G2 + (size_t)y*Gd + lane] = 1.f/(1.f+expf(-s));
    }
}

// ---------------- separable 5-tap max pool (window clipped at borders) -----------
__global__ void pool1d_k(const float* __restrict__ in, float* __restrict__ out, int sh){
    int i = blockIdx.x*256 + threadIdx.x;
    if (i >= NB*G3) return;
    int p = (i >> sh) & 63;
    int s = 1 << sh;
    float v = in[i];
    if (p >= 1)  v = fmaxf(v, in[i - s]);
    if (p >= 2)  v = fmaxf(v, in[i - 2*s]);
    if (p <= 62) v = fmaxf(v, in[i + s]);
    if (p <= 61) v = fmaxf(v, in[i + 2*s]);
    out[i] = v;
}

__global__ void eq_k(const float* __restrict__ a, const float* __restrict__ b, float* __restrict__ m){
    int i = blockIdx.x*256 + threadIdx.x;
    if (i >= NB*G3) return;
    m[i] = (a[i]==b[i]) ? 1.f : 0.f;
}
// supp(in:pooled mask, out:0/1), ss = supp?0:s
__global__ void supp_ss_k(const float* __restrict__ s, float* __restrict__ supp, float* __restrict__ ss){
    int i = blockIdx.x*256 + threadIdx.x;
    if (i >= NB*G3) return;
    bool sp = supp[i] > 0.f;
    supp[i] = sp ? 1.f : 0.f;
    ss[i]   = sp ? 0.f : s[i];
}
// mask |= (ss==mss) & ~supp
__global__ void upd_mask_k(float* __restrict__ mask, const float* __restrict__ ss,
                           const float* __restrict__ mss, const float* __restrict__ supp){
    int i = blockIdx.x*256 + threadIdx.x;
    if (i >= NB*G3) return;
    bool nm = (ss[i]==mss[i]) && (supp[i]==0.f);
    mask[i] = (mask[i]!=0.f || nm) ? 1.f : 0.f;
}

__global__ void init_k(int* cnt){ if (threadIdx.x < NB) cnt[threadIdx.x]=0; }

__global__ void compact_k(const float* __restrict__ mask, const float* __restrict__ s,
                          float* __restrict__ lv, int* __restrict__ li, int* __restrict__ cnt){
    int i = blockIdx.x*256 + threadIdx.x;
    if (i >= NB*G3) return;
    if (mask[i]!=0.f){
        int b = i >> 18;
        int pos = atomicAdd(&cnt[b],1);
        if (pos < CAPN){
            lv[(size_t)b*CAPN+pos] = s[i];
            li[(size_t)b*CAPN+pos] = i & (G3-1);
        }
    }
}

// ---------------- top-k (k=128): 128 rounds of block argmax, ties -> lower index --
__global__ void __launch_bounds__(256) topk_k(float* __restrict__ lv, const int* __restrict__ li,
                       const int* __restrict__ cnt, float* __restrict__ tv, int* __restrict__ ti){
    const int b = blockIdx.x;
    const int t = threadIdx.x;
    __shared__ float sv[256]; __shared__ int si[256]; __shared__ int sp[256];
    int n = cnt[b]; if (n > CAPN) n = CAPN;
    float* Lv = lv + (size_t)b*CAPN;
    const int* Li = li + (size_t)b*CAPN;
    for (int r=0; r<TOPKN; ++r){
        float bv = 0.f; int bi = 0x7fffffff; int bp = -1;
        for (int j=t; j<n; j+=256){
            float v = Lv[j];
            int  ix = Li[j];
            if (v > bv || (v == bv && bp >= 0 && ix < bi)) { bv=v; bi=ix; bp=j; }
        }
        sv[t]=bv; si[t]=bi; sp[t]=bp;
        __syncthreads();
        for (int off=128; off>0; off>>=1){
            if (t < off){
                float v2=sv[t+off];
                if (sp[t+off] >= 0 && (sp[t] < 0 || v2 > sv[t] || (v2==sv[t] && si[t+off] < si[t]))){
                    sv[t]=v2; si[t]=si[t+off]; sp[t]=sp[t+off];
                }
            }
            __syncthreads();
        }
        if (t==0){
            if (sp[0] >= 0 && sv[0] > 0.f){
                tv[b*TOPKN+r]=sv[0]; ti[b*TOPKN+r]=si[0];
                Lv[sp[0]] = -1.f;           // mark consumed
            } else { tv[b*TOPKN+r]=0.f; ti[b*TOPKN+r]=0; }
        }
        __syncthreads();
    }
}

// ---------------- per-detection bbox+clas heads + decode --------------------------
__global__ void __launch_bounds__(512) perdet_k(
    const float* __restrict__ neck,
    const float* __restrict__ tv, const int* __restrict__ ti,
    const float* __restrict__ bw1, const float* __restrict__ bb1,
    const float* __restrict__ bw2, const float* __restrict__ bb2,
    const float* __restrict__ bwf, const float* __restrict__ bbf,
    const float* __restrict__ lw1, const float* __restrict__ lb1,
    const float* __restrict__ lw2, const float* __restrict__ lb2,
    const float* __restrict__ lwf, const float* __restrict__ lbf,
    float* __restrict__ out)
{
    const int blk = blockIdx.x;
    const int b = blk >> 7, r = blk & 127;
    const int t = threadIdx.x;
    float score = tv[b*TOPKN + r];
    int   idx   = ti[b*TOPKN + r];
    float* orow = out + ((size_t)b*TOPKN + r)*43;
    if (!(score > DET_TH)){
        if (t < 43) orow[t] = 0.f;      // valid=0 zeroes whole row
        return;
    }
    const int iz = idx >> 12, iy = (idx>>6)&63, ix = idx&63;

    __shared__ float pin[CIN][125];     // 5^3 input patch, zero-padded
    __shared__ float h1s[27][HIDC];
    __shared__ float h2s[HIDC];
    __shared__ float raws[7+NCLASS];

    const float* inb = neck + (size_t)b*CIN*G3;
    for (int e=t; e<CIN*125; e+=512){
        int ci=e/125, q=e-ci*125;
        int pz=q/25, py=(q/5)%5, px=q%5;
        int gz=iz-2+pz, gy=iy-2+py, gx=ix-2+px;
        float v=0.f;
        if ((unsigned)gz<64u && (unsigned)gy<64u && (unsigned)gx<64u)
            v = inb[(size_t)ci*G3 + (size_t)gz*G2 + gy*Gd + gx];
        pin[ci][q]=v;
    }
    __syncthreads();

    for (int head=0; head<2; ++head){
        const float* w1 = head? lw1 : bw1;
        const float* b1 = head? lb1 : bb1;
        const float* w2 = head? lw2 : bw2;
        const float* b2 = head? lb2 : bb2;
        const float* wf = head? lwf : bwf;
        const float* bf = head? lbf : bbf;
        const int fdim  = head? NCLASS : 7;

        // hidden1 at the 27 positions around v (zero if position outside grid)
        for (int e=t; e<27*HIDC; e+=512){
            int co = e & 127, pos = e >> 7;
            int pdz=pos/9, pdy=(pos/3)%3, pdx=pos%3;
            int gz=iz-1+pdz, gy=iy-1+pdy, gx=ix-1+pdx;
            float acc = 0.f;
            if ((unsigned)gz<64u && (unsigned)gy<64u && (unsigned)gx<64u){
                acc = b1[co];
                const float* wco = w1 + (size_t)co*CIN*27;
                for (int ci=0; ci<CIN; ++ci){
                    const float* pr = pin[ci];
                    const float* wr = wco + ci*27;
                    #pragma unroll
                    for (int tz=0;tz<3;++tz)
                        #pragma unroll
                        for (int ty=0;ty<3;++ty)
                            #pragma unroll
                            for (int tx=0;tx<3;++tx)
                                acc = fmaf(pr[(pdz+tz)*25+(pdy+ty)*5+(pdx+tx)],
                                           wr[(tz*3+ty)*3+tx], acc);
                }
                acc = acc>0.f ? acc : 0.f;
            }
            h1s[pos][co]=acc;
        }
        __syncthreads();

        if (t < HIDC){
            float acc = b2[t];
            const float* wco = w2 + (size_t)t*HIDC*27;
            for (int pos=0; pos<27; ++pos){
                const float* hr = h1s[pos];
                for (int ci=0; ci<HIDC; ++ci)
                    acc = fmaf(hr[ci], wco[ci*27+pos], acc);
            }
            h2s[t] = acc>0.f ? acc : 0.f;
        }
        __syncthreads();

        if (t < fdim){
            float acc = bf[t];
            const float* wr = wf + t*HIDC;
            for (int ci=0; ci<HIDC; ++ci) acc = fmaf(h2s[ci], wr[ci], acc);
            raws[(head?7:0)+t] = acc;
        }
        __syncthreads();
    }

    if (t==0){
        const float vx = (float)(6.4/64.0);
        float cx = -3.2f + ((float)ix + 0.5f)*vx;
        float cy = -3.2f + ((float)iy + 0.5f)*vx;
        float cz = -3.2f + ((float)iz + 0.5f)*vx;
        float sx = 5.9f*(1.f/(1.f+expf(-raws[0]))) + 0.1f;
        float sy = 5.9f*(1.f/(1.f+expf(-raws[1]))) + 0.1f;
        float sz = 5.9f*(1.f/(1.f+expf(-raws[2]))) + 0.1f;
        float ox = 0.2f*tanhf(raws[3]);
        float oy = 0.2f*tanhf(raws[4]);
        float oz = 0.2f*tanhf(raws[5]);
        float yw = 1.6f*tanhf(raws[6]);
        orow[0]=cx+ox; orow[1]=cy+oy; orow[2]=cz+oz;
        orow[3]=sx; orow[4]=sy; orow[5]=sz;
        orow[6]=yw; orow[7]=score; orow[8]=1.f;
        float mx = raws[7];
        #pragma unroll
        for (int i=1;i<NCLASS;++i) mx = fmaxf(mx, raws[7+i]);
        float ev[NCLASS]; float sum=0.f;
        #pragma unroll
        for (int i=0;i<NCLASS;++i){ ev[i]=expf(raws[7+i]-mx); sum+=ev[i]; }
        float inv = 1.f/sum;
        #pragma unroll
        for (int i=0;i<NCLASS;++i) orow[9+i] = ev[i]*inv;
    }
}

extern "C" void kernel_launch(void* const* d_in, const int* in_sizes, int n_in,
                              void* d_out, int out_size, void* d_ws, size_t ws_size,
                              hipStream_t stream)
{
    (void)in_sizes; (void)n_in; (void)out_size;
    const float* neck = (const float*)d_in[0];
    const float* ce_w1=(const float*)d_in[1],  *ce_b1=(const float*)d_in[2];
    const float* ce_w2=(const float*)d_in[3],  *ce_b2=(const float*)d_in[4];
    const float* ce_wf=(const float*)d_in[5],  *ce_bf=(const float*)d_in[6];
    const float* bb_w1=(const float*)d_in[7],  *bb_b1=(const float*)d_in[8];
    const float* bb_w2=(const float*)d_in[9],  *bb_b2=(const float*)d_in[10];
    const float* bb_wf=(const float*)d_in[11], *bb_bf=(const float*)d_in[12];
    const float* cl_w1=(const float*)d_in[13], *cl_b1=(const float*)d_in[14];
    const float* cl_w2=(const float*)d_in[15], *cl_b2=(const float*)d_in[16];
    const float* cl_wf=(const float*)d_in[17], *cl_bf=(const float*)d_in[18];
    float* out = (float*)d_out;
    char* ws = (char*)d_ws;

    float* scores=(float*)(ws + 0);
    float* tA    =(float*)(ws + (2u<<20));
    float* tB    =(float*)(ws + (4u<<20));
    float* bufM  =(float*)(ws + (6u<<20));
    float* mask  =(float*)(ws + (8u<<20));
    float* supp  =(float*)(ws + (10u<<20));
    float* ssb   =(float*)(ws + (12u<<20));
    float* lv    =(float*)(ws + (14u<<20));
    int*   li    =(int*)  (ws + (14u<<20) + (512u<<10));
    float* tv    =(float*)(ws + (15u<<20));
    int*   ti    =(int*)  (ws + (15u<<20) + 4096);
    int*   cnt   =(int*)  (ws + (15u<<20) + 8192);
    float* wpk1  =(float*)(ws + (15u<<20) + 16384);   // 884,736 B
    float* wpk2  =(float*)(ws + (16u<<20));           // 1,769,472 B
    float* h1    =(float*)(ws + (18u<<20));

    // pick z-slab size by available workspace: need (Tz+2) planes of 2 MB
    size_t fixed = 18u<<20;
    size_t plane_bytes = (size_t)HIDC*G2*4;
    int Tz = 4;
    if (ws_size > fixed){
        size_t planes = (ws_size - fixed)/plane_bytes;
        if      (planes >= 66) Tz = 64;
        else if (planes >= 34) Tz = 32;
        else if (planes >= 18) Tz = 16;
        else if (planes >= 10) Tz = 8;
    }
    const int nplanes = Tz + 2;

    init_k<<<1, 64, 0, stream>>>(cnt);
    repack_k<<<(HIDC*CIN*27 +255)/256, 256, 0, stream>>>(ce_w1, wpk1, CIN);
    repack_k<<<(HIDC*HIDC*27+255)/256, 256, 0, stream>>>(ce_w2, wpk2, HIDC);

    for (int b=0; b<NB; ++b){
        const float* inb = neck + (size_t)b*CIN*G3;
        float* scb = scores + (size_t)b*G3;
        for (int z0=0; z0<Gd; z0+=Tz){
            conv1_k<<<dim3(64, nplanes), 256, 0, stream>>>(inb, wpk1, ce_b1, h1, z0, nplanes);
            conv2_k<<<dim3(64, Tz),      256, 0, stream>>>(h1, wpk2, ce_b2, ce_wf, ce_bf, scb, z0, nplanes);
        }
    }

    const int n = NB*G3, nb = n/256;
    // maxpool3d helper: x(sh=0) -> y(sh=6) -> z(sh=12)
    #define POOL3(SRC, DST) \
        pool1d_k<<<nb,256,0,stream>>>((SRC), tA, 0); \
        pool1d_k<<<nb,256,0,stream>>>(tA, tB, 6);    \
        pool1d_k<<<nb,256,0,stream>>>(tB, (DST), 12);

    POOL3(scores, bufM);
    eq_k<<<nb,256,0,stream>>>(scores, bufM, mask);
    for (int it=0; it<2; ++it){
        POOL3(mask, supp);
        supp_ss_k<<<nb,256,0,stream>>>(scores, supp, ssb);
        POOL3(ssb, bufM);
        upd_mask_k<<<nb,256,0,stream>>>(mask, ssb, bufM, supp);
    }
    #undef POOL3

    compact_k<<<nb,256,0,stream>>>(mask, scores, lv, li, cnt);
    topk_k<<<NB,256,0,stream>>>(lv, li, cnt, tv, ti);
    perdet_k<<<NB*TOPKN,512,0,stream>>>(neck, tv, ti,
        bb_w1,bb_b1,bb_w2,bb_b2,bb_wf,bb_bf,
        cl_w1,cl_b1,cl_w2,cl_b2,cl_wf,cl_bf, out);
}

// Round 2
// 8695.934 us; speedup vs baseline: 1.0394x; 1.0394x over previous
//
#include <hip/hip_runtime.h>
#include <math.h>

#define Gd 64
#define G2 4096
#define G3 262144
#define CIN 64
#define HIDC 128
#define NB 2
#define TOPKN 128
#define NCLASS 34
#define CAPN 65536
#define DET_TH 0.2f

typedef unsigned short u16;
typedef unsigned int u32;
typedef float f32x16 __attribute__((ext_vector_type(16)));
typedef short s16x8  __attribute__((ext_vector_type(8)));

__device__ __forceinline__ u16 f2bf(float x){
    u32 u = __float_as_uint(x);
    u32 r = u + 0x7fffu + ((u>>16)&1u);
    return (u16)(r>>16);
}

// ---------------- weight repack (conv1, fp32): w[co][ci][27] -> wpk[ci*27+tap][co]
__global__ void repack_k(const float* __restrict__ w, float* __restrict__ wpk, int ci_n){
    int i = blockIdx.x*256 + threadIdx.x;
    int total = HIDC*ci_n*27;
    if (i >= total) return;
    int co = i/(ci_n*27);
    int r  = i - co*(ci_n*27);
    wpk[(size_t)r*HIDC + co] = w[i];
}

// ---------------- weight repack (conv2, bf16 split): w[co][ci][27] ->
//   whi/wlo[((tap*8+chunk)*128+co)*16 + ci%16]
__global__ void repack2_k(const float* __restrict__ w, u16* __restrict__ whi, u16* __restrict__ wlo){
    int i = blockIdx.x*256 + threadIdx.x;
    if (i >= 27*128*128) return;
    int tap = i >> 14;
    int r   = i & 16383;
    int co  = r >> 7;
    int ci  = r & 127;
    float v = w[((size_t)co*128 + ci)*27 + tap];
    u16 h = f2bf(v);
    float hf = __uint_as_float(((u32)h)<<16);
    u16 l = f2bf(v - hf);
    size_t dst = ((size_t)(tap*8 + (ci>>4))*128 + co)*16 + (ci&15);
    whi[dst] = h; wlo[dst] = l;
}

// ---------------- conv1 (fp32 VALU): neck(64ch) -> h1 bf16 hi/lo channel-last ----
// h1 layout: [p][y][x 0..65 padded][128co], x=0 and x=65 are zero pads.
__global__ void __launch_bounds__(256,4) conv1_k(
    const float* __restrict__ in,      // batch-offset [CIN][G3]
    const float* __restrict__ wpk,     // [CIN*27][128]
    const float* __restrict__ b1,      // [128]
    u16* __restrict__ h1hi, u16* __restrict__ h1lo,
    int z0, int nplanes)
{
    const int y    = blockIdx.x;
    const int p    = blockIdx.y;
    const int z    = z0 - 1 + p;
    const int lane = threadIdx.x & 63;
    const int wv   = __builtin_amdgcn_readfirstlane(threadIdx.x >> 6);
    const int co0  = wv*32;

    __shared__ float sbuf[2][9][66];

    const size_t rowbase = ((size_t)p*64 + y)*66;   // in voxel units

    if (z < 0 || z >= Gd){   // halo plane outside grid: zero whole (p,y) row
        for (int e=threadIdx.x; e<66*128; e+=256){ h1hi[rowbase*128+e]=0; h1lo[rowbase*128+e]=0; }
        return;
    }
    // zero the x pads (x=0 and x=65)
    {
        int t = threadIdx.x;
        int x = (t<128)?0:65; int co = t&127;
        h1hi[(rowbase + x)*128 + co] = 0;
        h1lo[(rowbase + x)*128 + co] = 0;
    }

    float acc[32];
    #pragma unroll
    for (int j=0;j<32;++j) acc[j] = b1[co0+j];

    for (int e=threadIdx.x; e<9*66; e+=256){
        int row=e/66, col=e-row*66;
        int dz=row/3, dy=row-dz*3;
        int gz=z-1+dz, gy=y-1+dy, gx=col-1;
        float v=0.f;
        if ((unsigned)gz<64u && (unsigned)gy<64u && (unsigned)gx<64u)
            v = in[(size_t)gz*G2 + gy*Gd + gx];
        sbuf[0][row][col]=v;
    }
    __syncthreads();

    for (int ci=0; ci<CIN; ++ci){
        if (ci+1 < CIN){
            const float* ip = in + (size_t)(ci+1)*G3;
            int nbuf = (ci+1)&1;
            for (int e=threadIdx.x; e<9*66; e+=256){
                int row=e/66, col=e-row*66;
                int dz=row/3, dy=row-dz*3;
                int gz=z-1+dz, gy=y-1+dy, gx=col-1;
                float v=0.f;
                if ((unsigned)gz<64u && (unsigned)gy<64u && (unsigned)gx<64u)
                    v = ip[(size_t)gz*G2 + gy*Gd + gx];
                sbuf[nbuf][row][col]=v;
            }
        }
        const int bs = ci&1;
        float a[27];
        #pragma unroll
        for (int rr=0; rr<9; ++rr){
            a[rr*3+0]=sbuf[bs][rr][lane+0];
            a[rr*3+1]=sbuf[bs][rr][lane+1];
            a[rr*3+2]=sbuf[bs][rr][lane+2];
        }
        const float* wb = wpk + (size_t)ci*27*HIDC + co0;
        #pragma unroll
        for (int t=0;t<27;++t){
            const float* wr = wb + t*HIDC;
            #pragma unroll
            for (int j=0;j<32;++j) acc[j] = fmaf(a[t], wr[j], acc[j]);
        }
        __syncthreads();
    }
    // epilogue: relu, split to bf16 hi/lo, write channel-last (coalesced per lane)
    u16 hs[32], ls[32];
    #pragma unroll
    for (int j=0;j<32;++j){
        float v = acc[j] > 0.f ? acc[j] : 0.f;
        u16 h = f2bf(v);
        float hf = __uint_as_float(((u32)h)<<16);
        hs[j]=h; ls[j]=f2bf(v - hf);
    }
    size_t base = (rowbase + lane + 1)*128 + co0;
    u32 uh[16], ul[16];
    #pragma unroll
    for (int k=0;k<16;++k){
        uh[k] = (u32)hs[2*k] | ((u32)hs[2*k+1]<<16);
        ul[k] = (u32)ls[2*k] | ((u32)ls[2*k+1]<<16);
    }
    #pragma unroll
    for (int q=0;q<4;++q){
        uint4 vh; vh.x=uh[4*q]; vh.y=uh[4*q+1]; vh.z=uh[4*q+2]; vh.w=uh[4*q+3];
        uint4 vl; vl.x=ul[4*q]; vl.y=ul[4*q+1]; vl.z=ul[4*q+2]; vl.w=ul[4*q+3];
        ((uint4*)(h1hi + base))[q] = vh;
        ((uint4*)(h1lo + base))[q] = vl;
    }
}

// ---------------- conv2 (MFMA bf16x3) fused with wf-dot + sigmoid -> scores ------
// Block tile: co=128 x spatial(2z,1y,64x). 4 waves: cg=w&1 -> co half, sg=w>>1 -> z.
#define C2_ROWS 12
#define C2_UNITS (C2_ROWS*66*2)   // 1584 16B-units per array

__global__ void __launch_bounds__(256,3) conv2_mfma(
    const u16* __restrict__ h1hi, const u16* __restrict__ h1lo,
    const u16* __restrict__ whi,  const u16* __restrict__ wlo,
    const float* __restrict__ b2, const float* __restrict__ wf,
    const float* __restrict__ bf, float* __restrict__ scores, int z0)
{
    const int yt = blockIdx.x;       // 0..63
    const int zt = blockIdx.y;       // 0..Tz/2-1
    const int t  = threadIdx.x;
    const int lane = t & 63;
    const int w  = t >> 6;
    const int cg = w & 1;            // co in [64cg, 64cg+64)
    const int sg = w >> 1;           // local z 0/1
    const int n  = lane & 31;
    const int g  = lane >> 5;

    __shared__ uint4 sthi[C2_UNITS];
    __shared__ uint4 stlo[C2_UNITS];

    f32x16 acc[2][2];
    #pragma unroll
    for (int a=0;a<2;++a)
        #pragma unroll
        for (int b=0;b<2;++b)
            #pragma unroll
            for (int r=0;r<16;++r) acc[a][b][r]=0.f;

    const int aoff_u4 = (cg*64 + n)*2 + g;   // A-frag uint4 offset inside [128co][2]

    for (int c=0; c<8; ++c){
        __syncthreads();
        for (int u=t; u<C2_UNITS; u+=256){
            int row = u/132, rem = u-row*132;
            int x = rem>>1, gg = rem&1;
            int zr = row/3, yr = row-zr*3;
            int p = 2*zt + zr;
            int y = yt - 1 + yr;
            int pu = (row*66 + x)*2 + (gg ^ ((x>>2)&1));
            uint4 vh; vh.x=vh.y=vh.z=vh.w=0u;
            uint4 vl; vl.x=vl.y=vl.z=vl.w=0u;
            if ((unsigned)y < 64u){
                size_t off = (((size_t)p*64 + y)*66 + x)*128 + c*16 + gg*8;
                vh = *(const uint4*)(h1hi + off);
                vl = *(const uint4*)(h1lo + off);
            }
            sthi[pu]=vh; stlo[pu]=vl;
        }
        __syncthreads();
        for (int tap=0; tap<27; ++tap){
            int dz = tap/9, r9 = tap-dz*9;
            int dy = r9/3, dx = r9-dy*3;
            const uint4* wbh = (const uint4*)whi + (size_t)(tap*8+c)*256 + aoff_u4;
            const uint4* wbl = (const uint4*)wlo + (size_t)(tap*8+c)*256 + aoff_u4;
            s16x8 ah[2], al[2];
            #pragma unroll
            for (int mt=0; mt<2; ++mt){
                uint4 th = wbh[mt*64];
                uint4 tl = wbl[mt*64];
                ah[mt] = *(const s16x8*)&th;
                al[mt] = *(const s16x8*)&tl;
            }
            int rowb = ((sg+dz)*3 + dy)*66;
            #pragma unroll
            for (int j=0;j<2;++j){
                int xpos = j*32 + n + dx;
                int pu = (rowb + xpos)*2 + (g ^ ((xpos>>2)&1));
                uint4 bhq = sthi[pu], blq = stlo[pu];
                s16x8 bh = *(const s16x8*)&bhq;
                s16x8 bl = *(const s16x8*)&blq;
                #pragma unroll
                for (int mt=0; mt<2; ++mt){
                    acc[mt][j] = __builtin_amdgcn_mfma_f32_32x32x16_bf16(al[mt], bh, acc[mt][j],0,0,0);
                    acc[mt][j] = __builtin_amdgcn_mfma_f32_32x32x16_bf16(ah[mt], bl, acc[mt][j],0,0,0);
                    acc[mt][j] = __builtin_amdgcn_mfma_f32_32x32x16_bf16(ah[mt], bh, acc[mt][j],0,0,0);
                }
            }
        }
    }
    // epilogue: relu(acc+b2) . wf  (cross co-group reduce via LDS), sigmoid
    __syncthreads();
    float* red = (float*)sthi;
    float b2v[2][16], wfv[2][16];
    #pragma unroll
    for (int mt=0;mt<2;++mt)
        #pragma unroll
        for (int r=0;r<16;++r){
            int co = cg*64 + mt*32 + (r&3) + 8*(r>>2) + 4*g;
            b2v[mt][r]=b2[co]; wfv[mt][r]=wf[co];
        }
    float part[2];
    #pragma unroll
    for (int j=0;j<2;++j){
        float s=0.f;
        #pragma unroll
        for (int mt=0;mt<2;++mt)
            #pragma unroll
            for (int r=0;r<16;++r){
                float v = acc[mt][j][r] + b2v[mt][r];
                v = v>0.f?v:0.f;
                s = fmaf(v, wfv[mt][r], s);
            }
        part[j]=s;
    }
    int sidx0 = sg*64 + n;
    if (cg==0){ red[sidx0]=part[0]; red[sidx0+32]=part[1]; }
    __syncthreads();
    if (cg==1){
        float bfv = bf[0];
        int z = z0 + 2*zt + sg;
        #pragma unroll
        for (int j=0;j<2;++j){
            float tot = red[sidx0 + 32*j] + part[j] + bfv;
            scores[((size_t)z*64 + yt)*64 + j*32 + n] = 1.f/(1.f+expf(-tot));
        }
    }
}

// ---------------- separable 5-tap max pool (window clipped at borders) -----------
__global__ void pool1d_k(const float* __restrict__ in, float* __restrict__ out, int sh){
    int i = blockIdx.x*256 + threadIdx.x;
    if (i >= NB*G3) return;
    int p = (i >> sh) & 63;
    int s = 1 << sh;
    float v = in[i];
    if (p >= 1)  v = fmaxf(v, in[i - s]);
    if (p >= 2)  v = fmaxf(v, in[i - 2*s]);
    if (p <= 62) v = fmaxf(v, in[i + s]);
    if (p <= 61) v = fmaxf(v, in[i + 2*s]);
    out[i] = v;
}

__global__ void eq_k(const float* __restrict__ a, const float* __restrict__ b, float* __restrict__ m){
    int i = blockIdx.x*256 + threadIdx.x;
    if (i >= NB*G3) return;
    m[i] = (a[i]==b[i]) ? 1.f : 0.f;
}
__global__ void supp_ss_k(const float* __restrict__ s, float* __restrict__ supp, float* __restrict__ ss){
    int i = blockIdx.x*256 + threadIdx.x;
    if (i >= NB*G3) return;
    bool sp = supp[i] > 0.f;
    supp[i] = sp ? 1.f : 0.f;
    ss[i]   = sp ? 0.f : s[i];
}
__global__ void upd_mask_k(float* __restrict__ mask, const float* __restrict__ ss,
                           const float* __restrict__ mss, const float* __restrict__ supp){
    int i = blockIdx.x*256 + threadIdx.x;
    if (i >= NB*G3) return;
    bool nm = (ss[i]==mss[i]) && (supp[i]==0.f);
    mask[i] = (mask[i]!=0.f || nm) ? 1.f : 0.f;
}

__global__ void init_k(int* cnt){ if (threadIdx.x < NB) cnt[threadIdx.x]=0; }

__global__ void compact_k(const float* __restrict__ mask, const float* __restrict__ s,
                          float* __restrict__ lv, int* __restrict__ li, int* __restrict__ cnt){
    int i = blockIdx.x*256 + threadIdx.x;
    if (i >= NB*G3) return;
    if (mask[i]!=0.f){
        int b = i >> 18;
        int pos = atomicAdd(&cnt[b],1);
        if (pos < CAPN){
            lv[(size_t)b*CAPN+pos] = s[i];
            li[(size_t)b*CAPN+pos] = i & (G3-1);
        }
    }
}

// ---------------- top-k (k=128): 128 rounds of block argmax, ties -> lower index --
__global__ void __launch_bounds__(256) topk_k(float* __restrict__ lv, const int* __restrict__ li,
                       const int* __restrict__ cnt, float* __restrict__ tv, int* __restrict__ ti){
    const int b = blockIdx.x;
    const int t = threadIdx.x;
    __shared__ float sv[256]; __shared__ int si[256]; __shared__ int sp[256];
    int n = cnt[b]; if (n > CAPN) n = CAPN;
    float* Lv = lv + (size_t)b*CAPN;
    const int* Li = li + (size_t)b*CAPN;
    for (int r=0; r<TOPKN; ++r){
        float bv = 0.f; int bi = 0x7fffffff; int bp = -1;
        for (int j=t; j<n; j+=256){
            float v = Lv[j];
            int  ix = Li[j];
            if (v > bv || (v == bv && bp >= 0 && ix < bi)) { bv=v; bi=ix; bp=j; }
        }
        sv[t]=bv; si[t]=bi; sp[t]=bp;
        __syncthreads();
        for (int off=128; off>0; off>>=1){
            if (t < off){
                float v2=sv[t+off];
                if (sp[t+off] >= 0 && (sp[t] < 0 || v2 > sv[t] || (v2==sv[t] && si[t+off] < si[t]))){
                    sv[t]=v2; si[t]=si[t+off]; sp[t]=sp[t+off];
                }
            }
            __syncthreads();
        }
        if (t==0){
            if (sp[0] >= 0 && sv[0] > 0.f){
                tv[b*TOPKN+r]=sv[0]; ti[b*TOPKN+r]=si[0];
                Lv[sp[0]] = -1.f;
            } else { tv[b*TOPKN+r]=0.f; ti[b*TOPKN+r]=0; }
        }
        __syncthreads();
    }
}

// ---------------- per-detection bbox+clas heads + decode --------------------------
__global__ void __launch_bounds__(512) perdet_k(
    const float* __restrict__ neck,
    const float* __restrict__ tv, const int* __restrict__ ti,
    const float* __restrict__ bw1, const float* __restrict__ bb1,
    const float* __restrict__ bw2, const float* __restrict__ bb2,
    const float* __restrict__ bwf, const float* __restrict__ bbf,
    const float* __restrict__ lw1, const float* __restrict__ lb1,
    const float* __restrict__ lw2, const float* __restrict__ lb2,
    const float* __restrict__ lwf, const float* __restrict__ lbf,
    float* __restrict__ out)
{
    const int blk = blockIdx.x;
    const int b = blk >> 7, r = blk & 127;
    const int t = threadIdx.x;
    float score = tv[b*TOPKN + r];
    int   idx   = ti[b*TOPKN + r];
    float* orow = out + ((size_t)b*TOPKN + r)*43;
    if (!(score > DET_TH)){
        if (t < 43) orow[t] = 0.f;
        return;
    }
    const int iz = idx >> 12, iy = (idx>>6)&63, ix = idx&63;

    __shared__ float pin[CIN][125];
    __shared__ float h1s[27][HIDC];
    __shared__ float h2s[HIDC];
    __shared__ float raws[7+NCLASS];

    const float* inb = neck + (size_t)b*CIN*G3;
    for (int e=t; e<CIN*125; e+=512){
        int ci=e/125, q=e-ci*125;
        int pz=q/25, py=(q/5)%5, px=q%5;
        int gz=iz-2+pz, gy=iy-2+py, gx=ix-2+px;
        float v=0.f;
        if ((unsigned)gz<64u && (unsigned)gy<64u && (unsigned)gx<64u)
            v = inb[(size_t)ci*G3 + (size_t)gz*G2 + gy*Gd + gx];
        pin[ci][q]=v;
    }
    __syncthreads();

    for (int head=0; head<2; ++head){
        const float* w1 = head? lw1 : bw1;
        const float* b1 = head? lb1 : bb1;
        const float* w2 = head? lw2 : bw2;
        const float* b2 = head? lb2 : bb2;
        const float* wf = head? lwf : bwf;
        const float* bf = head? lbf : bbf;
        const int fdim  = head? NCLASS : 7;

        for (int e=t; e<27*HIDC; e+=512){
            int co = e & 127, pos = e >> 7;
            int pdz=pos/9, pdy=(pos/3)%3, pdx=pos%3;
            int gz=iz-1+pdz, gy=iy-1+pdy, gx=ix-1+pdx;
            float acc = 0.f;
            if ((unsigned)gz<64u && (unsigned)gy<64u && (unsigned)gx<64u){
                acc = b1[co];
                const float* wco = w1 + (size_t)co*CIN*27;
                for (int ci=0; ci<CIN; ++ci){
                    const float* pr = pin[ci];
                    const float* wr = wco + ci*27;
                    #pragma unroll
                    for (int tz=0;tz<3;++tz)
                        #pragma unroll
                        for (int ty=0;ty<3;++ty)
                            #pragma unroll
                            for (int tx=0;tx<3;++tx)
                                acc = fmaf(pr[(pdz+tz)*25+(pdy+ty)*5+(pdx+tx)],
                                           wr[(tz*3+ty)*3+tx], acc);
                }
                acc = acc>0.f ? acc : 0.f;
            }
            h1s[pos][co]=acc;
        }
        __syncthreads();

        if (t < HIDC){
            float acc = b2[t];
            const float* wco = w2 + (size_t)t*HIDC*27;
            for (int pos=0; pos<27; ++pos){
                const float* hr = h1s[pos];
                for (int ci=0; ci<HIDC; ++ci)
                    acc = fmaf(hr[ci], wco[ci*27+pos], acc);
            }
            h2s[t] = acc>0.f ? acc : 0.f;
        }
        __syncthreads();

        if (t < fdim){
            float acc = bf[t];
            const float* wr = wf + t*HIDC;
            for (int ci=0; ci<HIDC; ++ci) acc = fmaf(h2s[ci], wr[ci], acc);
            raws[(head?7:0)+t] = acc;
        }
        __syncthreads();
    }

    if (t==0){
        const float vx = (float)(6.4/64.0);
        float cx = -3.2f + ((float)ix + 0.5f)*vx;
        float cy = -3.2f + ((float)iy + 0.5f)*vx;
        float cz = -3.2f + ((float)iz + 0.5f)*vx;
        float sx = 5.9f*(1.f/(1.f+expf(-raws[0]))) + 0.1f;
        float sy = 5.9f*(1.f/(1.f+expf(-raws[1]))) + 0.1f;
        float sz = 5.9f*(1.f/(1.f+expf(-raws[2]))) + 0.1f;
        float ox = 0.2f*tanhf(raws[3]);
        float oy = 0.2f*tanhf(raws[4]);
        float oz = 0.2f*tanhf(raws[5]);
        float yw = 1.6f*tanhf(raws[6]);
        orow[0]=cx+ox; orow[1]=cy+oy; orow[2]=cz+oz;
        orow[3]=sx; orow[4]=sy; orow[5]=sz;
        orow[6]=yw; orow[7]=score; orow[8]=1.f;
        float mx = raws[7];
        #pragma unroll
        for (int i=1;i<NCLASS;++i) mx = fmaxf(mx, raws[7+i]);
        float ev[NCLASS]; float sum=0.f;
        #pragma unroll
        for (int i=0;i<NCLASS;++i){ ev[i]=expf(raws[7+i]-mx); sum+=ev[i]; }
        float inv = 1.f/sum;
        #pragma unroll
        for (int i=0;i<NCLASS;++i) orow[9+i] = ev[i]*inv;
    }
}

extern "C" void kernel_launch(void* const* d_in, const int* in_sizes, int n_in,
                              void* d_out, int out_size, void* d_ws, size_t ws_size,
                              hipStream_t stream)
{
    (void)in_sizes; (void)n_in; (void)out_size;
    const float* neck = (const float*)d_in[0];
    const float* ce_w1=(const float*)d_in[1],  *ce_b1=(const float*)d_in[2];
    const float* ce_w2=(const float*)d_in[3],  *ce_b2=(const float*)d_in[4];
    const float* ce_wf=(const float*)d_in[5],  *ce_bf=(const float*)d_in[6];
    const float* bb_w1=(const float*)d_in[7],  *bb_b1=(const float*)d_in[8];
    const float* bb_w2=(const float*)d_in[9],  *bb_b2=(const float*)d_in[10];
    const float* bb_wf=(const float*)d_in[11], *bb_bf=(const float*)d_in[12];
    const float* cl_w1=(const float*)d_in[13], *cl_b1=(const float*)d_in[14];
    const float* cl_w2=(const float*)d_in[15], *cl_b2=(const float*)d_in[16];
    const float* cl_wf=(const float*)d_in[17], *cl_bf=(const float*)d_in[18];
    float* out = (float*)d_out;
    char* ws = (char*)d_ws;

    float* scores=(float*)(ws + 0);
    float* tA    =(float*)(ws + (2u<<20));
    float* tB    =(float*)(ws + (4u<<20));
    float* bufM  =(float*)(ws + (6u<<20));
    float* mask  =(float*)(ws + (8u<<20));
    float* supp  =(float*)(ws + (10u<<20));
    float* ssb   =(float*)(ws + (12u<<20));
    float* lv    =(float*)(ws + (14u<<20));
    int*   li    =(int*)  (ws + (14u<<20) + (512u<<10));
    float* tv    =(float*)(ws + (15u<<20));
    int*   ti    =(int*)  (ws + (15u<<20) + 4096);
    int*   cnt   =(int*)  (ws + (15u<<20) + 8192);
    float* wpk1  =(float*)(ws + (15u<<20) + 16384);      // 884,736 B (conv1 fp32)
    u16*   whi   =(u16*)  (ws + (16u<<20));              // 884,736 B
    u16*   wlo   =(u16*)  (ws + (17u<<20));              // 884,736 B
    u16*   h1hi  =(u16*)  (ws + (20u<<20));

    // slab size selection: need 20MB + (Tz+2) planes * (64*66*128*2B) * 2 arrays
    const size_t plane_u16 = (size_t)64*66*128;          // per array, elems
    const size_t plane2_b  = plane_u16*2*2;              // hi+lo bytes = 2,162,688
    size_t fixed = 20u<<20;
    int Tz = 8;
    if      (ws_size >= fixed + 66*plane2_b) Tz = 64;
    else if (ws_size >= fixed + 34*plane2_b) Tz = 32;
    else if (ws_size >= fixed + 18*plane2_b) Tz = 16;
    const int nplanes = Tz + 2;
    u16* h1lo = h1hi + (size_t)nplanes*plane_u16;

    init_k<<<1, 64, 0, stream>>>(cnt);
    repack_k<<<(HIDC*CIN*27 +255)/256, 256, 0, stream>>>(ce_w1, wpk1, CIN);
    repack2_k<<<(27*128*128 +255)/256, 256, 0, stream>>>(ce_w2, whi, wlo);

    for (int b=0; b<NB; ++b){
        const float* inb = neck + (size_t)b*CIN*G3;
        float* scb = scores + (size_t)b*G3;
        for (int z0=0; z0<Gd; z0+=Tz){
            conv1_k<<<dim3(64, nplanes), 256, 0, stream>>>(inb, wpk1, ce_b1, h1hi, h1lo, z0, nplanes);
            conv2_mfma<<<dim3(64, Tz/2), 256, 0, stream>>>(h1hi, h1lo, whi, wlo, ce_b2, ce_wf, ce_bf, scb, z0);
        }
    }

    const int n = NB*G3, nb = n/256;
    #define POOL3(SRC, DST) \
        pool1d_k<<<nb,256,0,stream>>>((SRC), tA, 0); \
        pool1d_k<<<nb,256,0,stream>>>(tA, tB, 6);    \
        pool1d_k<<<nb,256,0,stream>>>(tB, (DST), 12);

    POOL3(scores, bufM);
    eq_k<<<nb,256,0,stream>>>(scores, bufM, mask);
    for (int it=0; it<2; ++it){
        POOL3(mask, supp);
        supp_ss_k<<<nb,256,0,stream>>>(scores, supp, ssb);
        POOL3(ssb, bufM);
        upd_mask_k<<<nb,256,0,stream>>>(mask, ssb, bufM, supp);
    }
    #undef POOL3

    compact_k<<<nb,256,0,stream>>>(mask, scores, lv, li, cnt);
    topk_k<<<NB,256,0,stream>>>(lv, li, cnt, tv, ti);
    perdet_k<<<NB*TOPKN,512,0,stream>>>(neck, tv, ti,
        bb_w1,bb_b1,bb_w2,bb_b2,bb_wf,bb_bf,
        cl_w1,cl_b1,cl_w2,cl_b2,cl_wf,cl_bf, out);
}

// Round 3
// 2997.422 us; speedup vs baseline: 3.0154x; 2.9011x over previous
//
#include <hip/hip_runtime.h>
#include <math.h>

#define Gd 64
#define G2 4096
#define G3 262144
#define CIN 64
#define HIDC 128
#define NB 2
#define TOPKN 128
#define NCLASS 34
#define CAPN 65536
#define DET_TH 0.2f

typedef unsigned short u16;
typedef unsigned int u32;
typedef float f32x16 __attribute__((ext_vector_type(16)));
typedef short s16x8  __attribute__((ext_vector_type(8)));

__device__ __forceinline__ u16 f2bf(float x){
    u32 u = __float_as_uint(x);
    u32 r = u + 0x7fffu + ((u>>16)&1u);
    return (u16)(r>>16);
}

// ---------------- weight repack conv1 (bf16 split): w[co][ci(64)][27] ->
//   whi/wlo[((tap*4+chunk)*128+co)*16 + ci%16]
__global__ void repack1b_k(const float* __restrict__ w, u16* __restrict__ whi, u16* __restrict__ wlo){
    int i = blockIdx.x*256 + threadIdx.x;
    if (i >= 27*128*64) return;
    int tap = i >> 13;
    int r   = i & 8191;
    int co  = r >> 6;
    int ci  = r & 63;
    float v = w[((size_t)co*64 + ci)*27 + tap];
    u16 h = f2bf(v);
    float hf = __uint_as_float(((u32)h)<<16);
    u16 l = f2bf(v - hf);
    size_t dst = ((size_t)(tap*4 + (ci>>4))*128 + co)*16 + (ci&15);
    whi[dst] = h; wlo[dst] = l;
}

// ---------------- weight repack conv2 (bf16 split): w[co][ci(128)][27] ->
//   whi/wlo[((tap*8+chunk)*128+co)*16 + ci%16]
__global__ void repack2_k(const float* __restrict__ w, u16* __restrict__ whi, u16* __restrict__ wlo){
    int i = blockIdx.x*256 + threadIdx.x;
    if (i >= 27*128*128) return;
    int tap = i >> 14;
    int r   = i & 16383;
    int co  = r >> 7;
    int ci  = r & 127;
    float v = w[((size_t)co*128 + ci)*27 + tap];
    u16 h = f2bf(v);
    float hf = __uint_as_float(((u32)h)<<16);
    u16 l = f2bf(v - hf);
    size_t dst = ((size_t)(tap*8 + (ci>>4))*128 + co)*16 + (ci&15);
    whi[dst] = h; wlo[dst] = l;
}

// ---------------- neck -> channel-last bf16 hi/lo: nb[z][y][x 0..65 pad][64ci] ---
__global__ void __launch_bounds__(256) nbconv_k(const float* __restrict__ in,
                                                u16* __restrict__ nhi, u16* __restrict__ nlo){
    const int zy = blockIdx.x;              // z*64+y
    const int t  = threadIdx.x;
    __shared__ u16 shi[64][68];             // [x][ci], padded stride
    __shared__ u16 slo[64][68];
    const int x = t & 63, wv = t >> 6;
    const float* src = in + (size_t)zy*64;
    #pragma unroll
    for (int r=0;r<16;++r){
        int ci = wv*16 + r;
        float v = src[(size_t)ci*G3 + x];
        u16 h = f2bf(v);
        float hf = __uint_as_float(((u32)h)<<16);
        shi[x][ci]=h; slo[x][ci]=f2bf(v-hf);
    }
    __syncthreads();
    const size_t obase = (size_t)zy*66*64;
    for (int e=t; e<64*32; e+=256){
        int xx=e>>5, cp=e&31;
        *(u32*)(nhi + obase + (size_t)(xx+1)*64 + 2*cp) = *(const u32*)&shi[xx][2*cp];
        *(u32*)(nlo + obase + (size_t)(xx+1)*64 + 2*cp) = *(const u32*)&slo[xx][2*cp];
    }
    if (t < 64){                            // x pads (x=0 and x=65)
        int px = (t<32)?0:65; int cp=t&31;
        *(u32*)(nhi + obase + (size_t)px*64 + 2*cp) = 0u;
        *(u32*)(nlo + obase + (size_t)px*64 + 2*cp) = 0u;
    }
}

#define C2_ROWS 12
#define C2_UNITS (C2_ROWS*66*2)   // 1584 16B-units per array

// ---------------- conv1 (MFMA bf16x3): nb(64ci) -> h1(128co) bf16 hi/lo ----------
// Block: y=yt, h1-plane pair (2zt, 2zt+1). Waves: cg=co-half, sg=plane of pair.
__global__ void __launch_bounds__(256,3) conv1_mfma(
    const u16* __restrict__ nhi, const u16* __restrict__ nlo,
    const u16* __restrict__ whi, const u16* __restrict__ wlo,
    const float* __restrict__ b1,
    u16* __restrict__ h1hi, u16* __restrict__ h1lo, int z0)
{
    const int yt = blockIdx.x;
    const int zt = blockIdx.y;
    const int t  = threadIdx.x;
    const int lane = t & 63;
    const int w  = t >> 6;
    const int cg = w & 1;
    const int sg = w >> 1;
    const int n  = lane & 31;
    const int g  = lane >> 5;

    __shared__ uint4 sthi[C2_UNITS];
    __shared__ uint4 stlo[C2_UNITS];

    f32x16 acc[2][2];
    #pragma unroll
    for (int a=0;a<2;++a)
        #pragma unroll
        for (int b=0;b<2;++b)
            #pragma unroll
            for (int r=0;r<16;++r) acc[a][b][r]=0.f;

    const int aoff_u4 = (cg*64 + n)*2 + g;

    for (int c=0; c<4; ++c){
        __syncthreads();
        for (int u=t; u<C2_UNITS; u+=256){
            int row = u/132, rem = u-row*132;
            int x = rem>>1, gg = rem&1;
            int zr = row/3, yr = row-zr*3;
            int zin = z0 - 2 + 2*zt + zr;
            int y = yt - 1 + yr;
            int pu = (row*66 + x)*2 + (gg ^ ((x>>2)&1));
            uint4 vh; vh.x=vh.y=vh.z=vh.w=0u;
            uint4 vl; vl.x=vl.y=vl.z=vl.w=0u;
            if ((unsigned)y < 64u && (unsigned)zin < 64u){
                size_t off = (((size_t)zin*64 + y)*66 + x)*64 + c*16 + gg*8;
                vh = *(const uint4*)(nhi + off);
                vl = *(const uint4*)(nlo + off);
            }
            sthi[pu]=vh; stlo[pu]=vl;
        }
        __syncthreads();
        for (int tap=0; tap<27; ++tap){
            int dz = tap/9, r9 = tap-dz*9;
            int dy = r9/3, dx = r9-dy*3;
            const uint4* wbh = (const uint4*)whi + (size_t)(tap*4+c)*256 + aoff_u4;
            const uint4* wbl = (const uint4*)wlo + (size_t)(tap*4+c)*256 + aoff_u4;
            s16x8 ah[2], al[2];
            #pragma unroll
            for (int mt=0; mt<2; ++mt){
                uint4 th = wbh[mt*64];
                uint4 tl = wbl[mt*64];
                ah[mt] = *(const s16x8*)&th;
                al[mt] = *(const s16x8*)&tl;
            }
            int rowb = ((sg+dz)*3 + dy)*66;
            #pragma unroll
            for (int j=0;j<2;++j){
                int xpos = j*32 + n + dx;
                int pu = (rowb + xpos)*2 + (g ^ ((xpos>>2)&1));
                uint4 bhq = sthi[pu], blq = stlo[pu];
                s16x8 bh = *(const s16x8*)&bhq;
                s16x8 bl = *(const s16x8*)&blq;
                #pragma unroll
                for (int mt=0; mt<2; ++mt){
                    acc[mt][j] = __builtin_amdgcn_mfma_f32_32x32x16_bf16(al[mt], bh, acc[mt][j],0,0,0);
                    acc[mt][j] = __builtin_amdgcn_mfma_f32_32x32x16_bf16(ah[mt], bl, acc[mt][j],0,0,0);
                    acc[mt][j] = __builtin_amdgcn_mfma_f32_32x32x16_bf16(ah[mt], bh, acc[mt][j],0,0,0);
                }
            }
        }
    }

    // epilogue: bias+relu+split -> h1 channel-last; zero for out-of-grid planes
    const int p = 2*zt + sg;
    const int zglob = z0 - 1 + p;
    const size_t rowbase = ((size_t)p*64 + yt)*66;
    {   // x pads: cg=0 -> x=0, cg=1 -> x=65 (both hi and lo), per plane sg
        size_t pbase = (rowbase + (cg?65:0))*128 + 2*lane;
        *(u32*)(h1hi + pbase) = 0u;
        *(u32*)(h1lo + pbase) = 0u;
    }
    const bool zok = ((unsigned)zglob < 64u);
    float bvals[2][16];
    #pragma unroll
    for (int mt=0;mt<2;++mt)
        #pragma unroll
        for (int r=0;r<16;++r)
            bvals[mt][r] = b1[cg*64 + mt*32 + (r&3) + 8*(r>>2) + 4*g];

    #pragma unroll
    for (int j=0;j<2;++j){
        size_t base = (rowbase + j*32 + n + 1)*128 + cg*64;
        #pragma unroll
        for (int mt=0;mt<2;++mt){
            u16 hs[16], ls[16];
            #pragma unroll
            for (int r=0;r<16;++r){
                float v = acc[mt][j][r] + bvals[mt][r];
                v = (zok && v>0.f) ? v : 0.f;
                u16 h = f2bf(v);
                float hf = __uint_as_float(((u32)h)<<16);
                hs[r]=h; ls[r]=f2bf(v-hf);
            }
            #pragma unroll
            for (int q=0;q<4;++q){
                size_t addr = base + mt*32 + q*8 + 4*g;
                uint2 sh, sl;
                sh.x = (u32)hs[4*q]   | ((u32)hs[4*q+1]<<16);
                sh.y = (u32)hs[4*q+2] | ((u32)hs[4*q+3]<<16);
                sl.x = (u32)ls[4*q]   | ((u32)ls[4*q+1]<<16);
                sl.y = (u32)ls[4*q+2] | ((u32)ls[4*q+3]<<16);
                *(uint2*)(h1hi + addr) = sh;
                *(uint2*)(h1lo + addr) = sl;
            }
        }
    }
}

// ---------------- conv2 (MFMA bf16x3) fused with wf-dot + sigmoid -> scores ------
__global__ void __launch_bounds__(256,3) conv2_mfma(
    const u16* __restrict__ h1hi, const u16* __restrict__ h1lo,
    const u16* __restrict__ whi,  const u16* __restrict__ wlo,
    const float* __restrict__ b2, const float* __restrict__ wf,
    const float* __restrict__ bf, float* __restrict__ scores, int z0)
{
    const int yt = blockIdx.x;
    const int zt = blockIdx.y;
    const int t  = threadIdx.x;
    const int lane = t & 63;
    const int w  = t >> 6;
    const int cg = w & 1;
    const int sg = w >> 1;
    const int n  = lane & 31;
    const int g  = lane >> 5;

    __shared__ uint4 sthi[C2_UNITS];
    __shared__ uint4 stlo[C2_UNITS];

    f32x16 acc[2][2];
    #pragma unroll
    for (int a=0;a<2;++a)
        #pragma unroll
        for (int b=0;b<2;++b)
            #pragma unroll
            for (int r=0;r<16;++r) acc[a][b][r]=0.f;

    const int aoff_u4 = (cg*64 + n)*2 + g;

    for (int c=0; c<8; ++c){
        __syncthreads();
        for (int u=t; u<C2_UNITS; u+=256){
            int row = u/132, rem = u-row*132;
            int x = rem>>1, gg = rem&1;
            int zr = row/3, yr = row-zr*3;
            int p = 2*zt + zr;
            int y = yt - 1 + yr;
            int pu = (row*66 + x)*2 + (gg ^ ((x>>2)&1));
            uint4 vh; vh.x=vh.y=vh.z=vh.w=0u;
            uint4 vl; vl.x=vl.y=vl.z=vl.w=0u;
            if ((unsigned)y < 64u){
                size_t off = (((size_t)p*64 + y)*66 + x)*128 + c*16 + gg*8;
                vh = *(const uint4*)(h1hi + off);
                vl = *(const uint4*)(h1lo + off);
            }
            sthi[pu]=vh; stlo[pu]=vl;
        }
        __syncthreads();
        for (int tap=0; tap<27; ++tap){
            int dz = tap/9, r9 = tap-dz*9;
            int dy = r9/3, dx = r9-dy*3;
            const uint4* wbh = (const uint4*)whi + (size_t)(tap*8+c)*256 + aoff_u4;
            const uint4* wbl = (const uint4*)wlo + (size_t)(tap*8+c)*256 + aoff_u4;
            s16x8 ah[2], al[2];
            #pragma unroll
            for (int mt=0; mt<2; ++mt){
                uint4 th = wbh[mt*64];
                uint4 tl = wbl[mt*64];
                ah[mt] = *(const s16x8*)&th;
                al[mt] = *(const s16x8*)&tl;
            }
            int rowb = ((sg+dz)*3 + dy)*66;
            #pragma unroll
            for (int j=0;j<2;++j){
                int xpos = j*32 + n + dx;
                int pu = (rowb + xpos)*2 + (g ^ ((xpos>>2)&1));
                uint4 bhq = sthi[pu], blq = stlo[pu];
                s16x8 bh = *(const s16x8*)&bhq;
                s16x8 bl = *(const s16x8*)&blq;
                #pragma unroll
                for (int mt=0; mt<2; ++mt){
                    acc[mt][j] = __builtin_amdgcn_mfma_f32_32x32x16_bf16(al[mt], bh, acc[mt][j],0,0,0);
                    acc[mt][j] = __builtin_amdgcn_mfma_f32_32x32x16_bf16(ah[mt], bl, acc[mt][j],0,0,0);
                    acc[mt][j] = __builtin_amdgcn_mfma_f32_32x32x16_bf16(ah[mt], bh, acc[mt][j],0,0,0);
                }
            }
        }
    }
    __syncthreads();
    float* red = (float*)sthi;
    float b2v[2][16], wfv[2][16];
    #pragma unroll
    for (int mt=0;mt<2;++mt)
        #pragma unroll
        for (int r=0;r<16;++r){
            int co = cg*64 + mt*32 + (r&3) + 8*(r>>2) + 4*g;
            b2v[mt][r]=b2[co]; wfv[mt][r]=wf[co];
        }
    float part[2];
    #pragma unroll
    for (int j=0;j<2;++j){
        float s=0.f;
        #pragma unroll
        for (int mt=0;mt<2;++mt)
            #pragma unroll
            for (int r=0;r<16;++r){
                float v = acc[mt][j][r] + b2v[mt][r];
                v = v>0.f?v:0.f;
                s = fmaf(v, wfv[mt][r], s);
            }
        part[j]=s;
    }
    int sidx0 = sg*64 + n;
    if (cg==0){ red[sidx0]=part[0]; red[sidx0+32]=part[1]; }
    __syncthreads();
    if (cg==1){
        float bfv = bf[0];
        int z = z0 + 2*zt + sg;
        #pragma unroll
        for (int j=0;j<2;++j){
            float tot = red[sidx0 + 32*j] + part[j] + bfv;
            scores[((size_t)z*64 + yt)*64 + j*32 + n] = 1.f/(1.f+expf(-tot));
        }
    }
}

// ---------------- separable 5-tap max pool ---------------------------------------
__global__ void pool1d_k(const float* __restrict__ in, float* __restrict__ out, int sh){
    int i = blockIdx.x*256 + threadIdx.x;
    if (i >= NB*G3) return;
    int p = (i >> sh) & 63;
    int s = 1 << sh;
    float v = in[i];
    if (p >= 1)  v = fmaxf(v, in[i - s]);
    if (p >= 2)  v = fmaxf(v, in[i - 2*s]);
    if (p <= 62) v = fmaxf(v, in[i + s]);
    if (p <= 61) v = fmaxf(v, in[i + 2*s]);
    out[i] = v;
}

__global__ void eq_k(const float* __restrict__ a, const float* __restrict__ b, float* __restrict__ m){
    int i = blockIdx.x*256 + threadIdx.x;
    if (i >= NB*G3) return;
    m[i] = (a[i]==b[i]) ? 1.f : 0.f;
}
__global__ void supp_ss_k(const float* __restrict__ s, float* __restrict__ supp, float* __restrict__ ss){
    int i = blockIdx.x*256 + threadIdx.x;
    if (i >= NB*G3) return;
    bool sp = supp[i] > 0.f;
    supp[i] = sp ? 1.f : 0.f;
    ss[i]   = sp ? 0.f : s[i];
}
__global__ void upd_mask_k(float* __restrict__ mask, const float* __restrict__ ss,
                           const float* __restrict__ mss, const float* __restrict__ supp){
    int i = blockIdx.x*256 + threadIdx.x;
    if (i >= NB*G3) return;
    bool nm = (ss[i]==mss[i]) && (supp[i]==0.f);
    mask[i] = (mask[i]!=0.f || nm) ? 1.f : 0.f;
}

__global__ void init_k(int* cnt){ if (threadIdx.x < NB) cnt[threadIdx.x]=0; }

__global__ void compact_k(const float* __restrict__ mask, const float* __restrict__ s,
                          float* __restrict__ lv, int* __restrict__ li, int* __restrict__ cnt){
    int i = blockIdx.x*256 + threadIdx.x;
    if (i >= NB*G3) return;
    if (mask[i]!=0.f){
        int b = i >> 18;
        int pos = atomicAdd(&cnt[b],1);
        if (pos < CAPN){
            lv[(size_t)b*CAPN+pos] = s[i];
            li[(size_t)b*CAPN+pos] = i & (G3-1);
        }
    }
}

// ---------------- top-k (k=128) ----------------------------------------------------
__global__ void __launch_bounds__(256) topk_k(float* __restrict__ lv, const int* __restrict__ li,
                       const int* __restrict__ cnt, float* __restrict__ tv, int* __restrict__ ti){
    const int b = blockIdx.x;
    const int t = threadIdx.x;
    __shared__ float sv[256]; __shared__ int si[256]; __shared__ int sp[256];
    int n = cnt[b]; if (n > CAPN) n = CAPN;
    float* Lv = lv + (size_t)b*CAPN;
    const int* Li = li + (size_t)b*CAPN;
    for (int r=0; r<TOPKN; ++r){
        float bv = 0.f; int bi = 0x7fffffff; int bp = -1;
        for (int j=t; j<n; j+=256){
            float v = Lv[j];
            int  ix = Li[j];
            if (v > bv || (v == bv && bp >= 0 && ix < bi)) { bv=v; bi=ix; bp=j; }
        }
        sv[t]=bv; si[t]=bi; sp[t]=bp;
        __syncthreads();
        for (int off=128; off>0; off>>=1){
            if (t < off){
                float v2=sv[t+off];
                if (sp[t+off] >= 0 && (sp[t] < 0 || v2 > sv[t] || (v2==sv[t] && si[t+off] < si[t]))){
                    sv[t]=v2; si[t]=si[t+off]; sp[t]=sp[t+off];
                }
            }
            __syncthreads();
        }
        if (t==0){
            if (sp[0] >= 0 && sv[0] > 0.f){
                tv[b*TOPKN+r]=sv[0]; ti[b*TOPKN+r]=si[0];
                Lv[sp[0]] = -1.f;
            } else { tv[b*TOPKN+r]=0.f; ti[b*TOPKN+r]=0; }
        }
        __syncthreads();
    }
}

// ---------------- per-detection bbox+clas heads + decode --------------------------
__global__ void __launch_bounds__(512) perdet_k(
    const float* __restrict__ neck,
    const float* __restrict__ tv, const int* __restrict__ ti,
    const float* __restrict__ bw1, const float* __restrict__ bb1,
    const float* __restrict__ bw2, const float* __restrict__ bb2,
    const float* __restrict__ bwf, const float* __restrict__ bbf,
    const float* __restrict__ lw1, const float* __restrict__ lb1,
    const float* __restrict__ lw2, const float* __restrict__ lb2,
    const float* __restrict__ lwf, const float* __restrict__ lbf,
    float* __restrict__ out)
{
    const int blk = blockIdx.x;
    const int b = blk >> 7, r = blk & 127;
    const int t = threadIdx.x;
    float score = tv[b*TOPKN + r];
    int   idx   = ti[b*TOPKN + r];
    float* orow = out + ((size_t)b*TOPKN + r)*43;
    if (!(score > DET_TH)){
        if (t < 43) orow[t] = 0.f;
        return;
    }
    const int iz = idx >> 12, iy = (idx>>6)&63, ix = idx&63;

    __shared__ float pin[CIN][125];
    __shared__ float h1s[27][HIDC];
    __shared__ float h2s[HIDC];
    __shared__ float raws[7+NCLASS];

    const float* inb = neck + (size_t)b*CIN*G3;
    for (int e=t; e<CIN*125; e+=512){
        int ci=e/125, q=e-ci*125;
        int pz=q/25, py=(q/5)%5, px=q%5;
        int gz=iz-2+pz, gy=iy-2+py, gx=ix-2+px;
        float v=0.f;
        if ((unsigned)gz<64u && (unsigned)gy<64u && (unsigned)gx<64u)
            v = inb[(size_t)ci*G3 + (size_t)gz*G2 + gy*Gd + gx];
        pin[ci][q]=v;
    }
    __syncthreads();

    for (int head=0; head<2; ++head){
        const float* w1 = head? lw1 : bw1;
        const float* b1 = head? lb1 : bb1;
        const float* w2 = head? lw2 : bw2;
        const float* b2 = head? lb2 : bb2;
        const float* wf = head? lwf : bwf;
        const float* bf = head? lbf : bbf;
        const int fdim  = head? NCLASS : 7;

        for (int e=t; e<27*HIDC; e+=512){
            int co = e & 127, pos = e >> 7;
            int pdz=pos/9, pdy=(pos/3)%3, pdx=pos%3;
            int gz=iz-1+pdz, gy=iy-1+pdy, gx=ix-1+pdx;
            float acc = 0.f;
            if ((unsigned)gz<64u && (unsigned)gy<64u && (unsigned)gx<64u){
                acc = b1[co];
                const float* wco = w1 + (size_t)co*CIN*27;
                for (int ci=0; ci<CIN; ++ci){
                    const float* pr = pin[ci];
                    const float* wr = wco + ci*27;
                    #pragma unroll
                    for (int tz=0;tz<3;++tz)
                        #pragma unroll
                        for (int ty=0;ty<3;++ty)
                            #pragma unroll
                            for (int tx=0;tx<3;++tx)
                                acc = fmaf(pr[(pdz+tz)*25+(pdy+ty)*5+(pdx+tx)],
                                           wr[(tz*3+ty)*3+tx], acc);
                }
                acc = acc>0.f ? acc : 0.f;
            }
            h1s[pos][co]=acc;
        }
        __syncthreads();

        if (t < HIDC){
            float acc = b2[t];
            const float* wco = w2 + (size_t)t*HIDC*27;
            for (int pos=0; pos<27; ++pos){
                const float* hr = h1s[pos];
                for (int ci=0; ci<HIDC; ++ci)
                    acc = fmaf(hr[ci], wco[ci*27+pos], acc);
            }
            h2s[t] = acc>0.f ? acc : 0.f;
        }
        __syncthreads();

        if (t < fdim){
            float acc = bf[t];
            const float* wr = wf + t*HIDC;
            for (int ci=0; ci<HIDC; ++ci) acc = fmaf(h2s[ci], wr[ci], acc);
            raws[(head?7:0)+t] = acc;
        }
        __syncthreads();
    }

    if (t==0){
        const float vx = (float)(6.4/64.0);
        float cx = -3.2f + ((float)ix + 0.5f)*vx;
        float cy = -3.2f + ((float)iy + 0.5f)*vx;
        float cz = -3.2f + ((float)iz + 0.5f)*vx;
        float sx = 5.9f*(1.f/(1.f+expf(-raws[0]))) + 0.1f;
        float sy = 5.9f*(1.f/(1.f+expf(-raws[1]))) + 0.1f;
        float sz = 5.9f*(1.f/(1.f+expf(-raws[2]))) + 0.1f;
        float ox = 0.2f*tanhf(raws[3]);
        float oy = 0.2f*tanhf(raws[4]);
        float oz = 0.2f*tanhf(raws[5]);
        float yw = 1.6f*tanhf(raws[6]);
        orow[0]=cx+ox; orow[1]=cy+oy; orow[2]=cz+oz;
        orow[3]=sx; orow[4]=sy; orow[5]=sz;
        orow[6]=yw; orow[7]=score; orow[8]=1.f;
        float mx = raws[7];
        #pragma unroll
        for (int i=1;i<NCLASS;++i) mx = fmaxf(mx, raws[7+i]);
        float ev[NCLASS]; float sum=0.f;
        #pragma unroll
        for (int i=0;i<NCLASS;++i){ ev[i]=expf(raws[7+i]-mx); sum+=ev[i]; }
        float inv = 1.f/sum;
        #pragma unroll
        for (int i=0;i<NCLASS;++i) orow[9+i] = ev[i]*inv;
    }
}

extern "C" void kernel_launch(void* const* d_in, const int* in_sizes, int n_in,
                              void* d_out, int out_size, void* d_ws, size_t ws_size,
                              hipStream_t stream)
{
    (void)in_sizes; (void)n_in; (void)out_size;
    const float* neck = (const float*)d_in[0];
    const float* ce_w1=(const float*)d_in[1],  *ce_b1=(const float*)d_in[2];
    const float* ce_w2=(const float*)d_in[3],  *ce_b2=(const float*)d_in[4];
    const float* ce_wf=(const float*)d_in[5],  *ce_bf=(const float*)d_in[6];
    const float* bb_w1=(const float*)d_in[7],  *bb_b1=(const float*)d_in[8];
    const float* bb_w2=(const float*)d_in[9],  *bb_b2=(const float*)d_in[10];
    const float* bb_wf=(const float*)d_in[11], *bb_bf=(const float*)d_in[12];
    const float* cl_w1=(const float*)d_in[13], *cl_b1=(const float*)d_in[14];
    const float* cl_w2=(const float*)d_in[15], *cl_b2=(const float*)d_in[16];
    const float* cl_wf=(const float*)d_in[17], *cl_bf=(const float*)d_in[18];
    float* out = (float*)d_out;
    char* ws = (char*)d_ws;

    float* scores=(float*)(ws + 0);
    float* tA    =(float*)(ws + (2u<<20));
    float* tB    =(float*)(ws + (4u<<20));
    float* bufM  =(float*)(ws + (6u<<20));
    float* mask  =(float*)(ws + (8u<<20));
    float* supp  =(float*)(ws + (10u<<20));
    float* ssb   =(float*)(ws + (12u<<20));
    float* lv    =(float*)(ws + (14u<<20));
    int*   li    =(int*)  (ws + (14u<<20) + (512u<<10));
    float* tv    =(float*)(ws + (15u<<20));
    int*   ti    =(int*)  (ws + (15u<<20) + 4096);
    int*   cnt   =(int*)  (ws + (15u<<20) + 8192);
    u16*   whi1  =(u16*)  (ws + (15u<<20) + 16384);      // 442,368 B
    u16*   wlo1  =(u16*)  (ws + (15u<<20) + (512u<<10)); // 442,368 B
    u16*   whi2  =(u16*)  (ws + (16u<<20));              // 884,736 B
    u16*   wlo2  =(u16*)  (ws + (17u<<20));              // 884,736 B
    u16*   nbhi  =(u16*)  (ws + (18u<<20));              // 33 MB
    u16*   nblo  =(u16*)  (ws + (51u<<20));              // 33 MB
    u16*   h1hi  =(u16*)  (ws + (84u<<20));

    // slab size selection: need 84MB + (Tz+2) planes * 2.16MB (hi+lo)
    const size_t plane_u16 = (size_t)64*66*128;          // elems per plane per array
    const size_t plane2_b  = plane_u16*2*2;
    const size_t fixedb = 84u<<20;
    int Tz = 4;
    if      (ws_size >= fixedb + 66*plane2_b) Tz = 64;
    else if (ws_size >= fixedb + 34*plane2_b) Tz = 32;
    else if (ws_size >= fixedb + 18*plane2_b) Tz = 16;
    else if (ws_size >= fixedb + 10*plane2_b) Tz = 8;
    const int nplanes = Tz + 2;
    u16* h1lo = h1hi + (size_t)nplanes*plane_u16;

    init_k<<<1, 64, 0, stream>>>(cnt);
    repack1b_k<<<(27*128*64 +255)/256, 256, 0, stream>>>(ce_w1, whi1, wlo1);
    repack2_k<<<(27*128*128+255)/256, 256, 0, stream>>>(ce_w2, whi2, wlo2);

    for (int b=0; b<NB; ++b){
        const float* inb = neck + (size_t)b*CIN*G3;
        float* scb = scores + (size_t)b*G3;
        nbconv_k<<<4096, 256, 0, stream>>>(inb, nbhi, nblo);
        for (int z0=0; z0<Gd; z0+=Tz){
            conv1_mfma<<<dim3(64, nplanes/2), 256, 0, stream>>>(nbhi, nblo, whi1, wlo1, ce_b1, h1hi, h1lo, z0);
            conv2_mfma<<<dim3(64, Tz/2),      256, 0, stream>>>(h1hi, h1lo, whi2, wlo2, ce_b2, ce_wf, ce_bf, scb, z0);
        }
    }

    const int n = NB*G3, nb = n/256;
    #define POOL3(SRC, DST) \
        pool1d_k<<<nb,256,0,stream>>>((SRC), tA, 0); \
        pool1d_k<<<nb,256,0,stream>>>(tA, tB, 6);    \
        pool1d_k<<<nb,256,0,stream>>>(tB, (DST), 12);

    POOL3(scores, bufM);
    eq_k<<<nb,256,0,stream>>>(scores, bufM, mask);
    for (int it=0; it<2; ++it){
        POOL3(mask, supp);
        supp_ss_k<<<nb,256,0,stream>>>(scores, supp, ssb);
        POOL3(ssb, bufM);
        upd_mask_k<<<nb,256,0,stream>>>(mask, ssb, bufM, supp);
    }
    #undef POOL3

    compact_k<<<nb,256,0,stream>>>(mask, scores, lv, li, cnt);
    topk_k<<<NB,256,0,stream>>>(lv, li, cnt, tv, ti);
    perdet_k<<<NB*TOPKN,512,0,stream>>>(neck, tv, ti,
        bb_w1,bb_b1,bb_w2,bb_b2,bb_wf,bb_bf,
        cl_w1,cl_b1,cl_w2,cl_b2,cl_wf,cl_bf, out);
}

// Round 4
// 2761.512 us; speedup vs baseline: 3.2730x; 1.0854x over previous
//
#include <hip/hip_runtime.h>
#include <math.h>

#define Gd 64
#define G2 4096
#define G3 262144
#define CIN 64
#define HIDC 128
#define NB 2
#define TOPKN 128
#define NCLASS 34
#define CAPN 65536
#define DET_TH 0.2f

typedef unsigned short u16;
typedef unsigned int u32;
typedef float f32x16 __attribute__((ext_vector_type(16)));
typedef short s16x8  __attribute__((ext_vector_type(8)));

__device__ __forceinline__ u16 f2bf(float x){
    u32 u = __float_as_uint(x);
    u32 r = u + 0x7fffu + ((u>>16)&1u);
    return (u16)(r>>16);
}

// ---------------- weight repack conv1 (bf16 split) -------------------------------
__global__ void repack1b_k(const float* __restrict__ w, u16* __restrict__ whi, u16* __restrict__ wlo){
    int i = blockIdx.x*256 + threadIdx.x;
    if (i >= 27*128*64) return;
    int tap = i >> 13;
    int r   = i & 8191;
    int co  = r >> 6;
    int ci  = r & 63;
    float v = w[((size_t)co*64 + ci)*27 + tap];
    u16 h = f2bf(v);
    float hf = __uint_as_float(((u32)h)<<16);
    u16 l = f2bf(v - hf);
    size_t dst = ((size_t)(tap*4 + (ci>>4))*128 + co)*16 + (ci&15);
    whi[dst] = h; wlo[dst] = l;
}

// ---------------- weight repack conv2 (bf16 split) -------------------------------
__global__ void repack2_k(const float* __restrict__ w, u16* __restrict__ whi, u16* __restrict__ wlo){
    int i = blockIdx.x*256 + threadIdx.x;
    if (i >= 27*128*128) return;
    int tap = i >> 14;
    int r   = i & 16383;
    int co  = r >> 7;
    int ci  = r & 127;
    float v = w[((size_t)co*128 + ci)*27 + tap];
    u16 h = f2bf(v);
    float hf = __uint_as_float(((u32)h)<<16);
    u16 l = f2bf(v - hf);
    size_t dst = ((size_t)(tap*8 + (ci>>4))*128 + co)*16 + (ci&15);
    whi[dst] = h; wlo[dst] = l;
}

// ---------------- neck -> channel-last bf16 hi/lo --------------------------------
__global__ void __launch_bounds__(256) nbconv_k(const float* __restrict__ in,
                                                u16* __restrict__ nhi, u16* __restrict__ nlo){
    const int zy = blockIdx.x;
    const int t  = threadIdx.x;
    __shared__ u16 shi[64][68];
    __shared__ u16 slo[64][68];
    const int x = t & 63, wv = t >> 6;
    const float* src = in + (size_t)zy*64;
    #pragma unroll
    for (int r=0;r<16;++r){
        int ci = wv*16 + r;
        float v = src[(size_t)ci*G3 + x];
        u16 h = f2bf(v);
        float hf = __uint_as_float(((u32)h)<<16);
        shi[x][ci]=h; slo[x][ci]=f2bf(v-hf);
    }
    __syncthreads();
    const size_t obase = (size_t)zy*66*64;
    for (int e=t; e<64*32; e+=256){
        int xx=e>>5, cp=e&31;
        *(u32*)(nhi + obase + (size_t)(xx+1)*64 + 2*cp) = *(const u32*)&shi[xx][2*cp];
        *(u32*)(nlo + obase + (size_t)(xx+1)*64 + 2*cp) = *(const u32*)&slo[xx][2*cp];
    }
    if (t < 64){
        int px = (t<32)?0:65; int cp=t&31;
        *(u32*)(nhi + obase + (size_t)px*64 + 2*cp) = 0u;
        *(u32*)(nlo + obase + (size_t)px*64 + 2*cp) = 0u;
    }
}

#define C2_UNITS (12*66*2)   // 1584 16B-units per array

// XCD-aware decode: xcd = b&7 owns yt band [xcd*8, xcd*8+8), sweeps zt ascending.
__device__ __forceinline__ void xcd_decode(int b, int& yt, int& zt){
    int xcd = b & 7, j = b >> 3;
    yt = xcd*8 + (j & 7);
    zt = j >> 3;
}

// ---------------- conv1 (MFMA bf16x3): nb(64ci) -> h1(128co) bf16 hi/lo ----------
__global__ void __launch_bounds__(256,3) conv1_mfma(
    const u16* __restrict__ nhi, const u16* __restrict__ nlo,
    const u16* __restrict__ whi, const u16* __restrict__ wlo,
    const float* __restrict__ b1,
    u16* __restrict__ h1hi, u16* __restrict__ h1lo, int z0)
{
    int yt, zt; xcd_decode(blockIdx.x, yt, zt);
    const int t  = threadIdx.x;
    const int lane = t & 63;
    const int w  = t >> 6;
    const int cg = w & 1;
    const int sg = w >> 1;
    const int n  = lane & 31;
    const int g  = lane >> 5;

    __shared__ uint4 sthi[C2_UNITS];
    __shared__ uint4 stlo[C2_UNITS];

    f32x16 acc[2][2];
    #pragma unroll
    for (int a=0;a<2;++a)
        #pragma unroll
        for (int b2_=0;b2_<2;++b2_)
            #pragma unroll
            for (int r=0;r<16;++r) acc[a][b2_][r]=0.f;

    const int aoff_u4 = (cg*64 + n)*2 + g;

    for (int c=0; c<4; ++c){
        __syncthreads();
        for (int u=t; u<C2_UNITS; u+=256){
            int row = u/132, rem = u-row*132;
            int x = rem>>1, gg = rem&1;
            int zr = row/3, yr = row-zr*3;
            int zin = z0 - 2 + 2*zt + zr;
            int y = yt - 1 + yr;
            int pu = (row*66 + x)*2 + (gg ^ ((x>>2)&1));
            uint4 vh; vh.x=vh.y=vh.z=vh.w=0u;
            uint4 vl; vl.x=vl.y=vl.z=vl.w=0u;
            if ((unsigned)y < 64u && (unsigned)zin < 64u){
                size_t off = (((size_t)zin*64 + y)*66 + x)*64 + c*16 + gg*8;
                vh = *(const uint4*)(nhi + off);
                vl = *(const uint4*)(nlo + off);
            }
            sthi[pu]=vh; stlo[pu]=vl;
        }
        __syncthreads();
        for (int tap=0; tap<27; ++tap){
            int dz = tap/9, r9 = tap-dz*9;
            int dy = r9/3, dx = r9-dy*3;
            const uint4* wbh = (const uint4*)whi + (size_t)(tap*4+c)*256 + aoff_u4;
            const uint4* wbl = (const uint4*)wlo + (size_t)(tap*4+c)*256 + aoff_u4;
            s16x8 ah[2], al[2];
            #pragma unroll
            for (int mt=0; mt<2; ++mt){
                uint4 th = wbh[mt*64];
                uint4 tl = wbl[mt*64];
                ah[mt] = *(const s16x8*)&th;
                al[mt] = *(const s16x8*)&tl;
            }
            int rowb = ((sg+dz)*3 + dy)*66;
            #pragma unroll
            for (int j=0;j<2;++j){
                int xpos = j*32 + n + dx;
                int pu = (rowb + xpos)*2 + (g ^ ((xpos>>2)&1));
                uint4 bhq = sthi[pu], blq = stlo[pu];
                s16x8 bh = *(const s16x8*)&bhq;
                s16x8 bl = *(const s16x8*)&blq;
                #pragma unroll
                for (int mt=0; mt<2; ++mt){
                    acc[mt][j] = __builtin_amdgcn_mfma_f32_32x32x16_bf16(al[mt], bh, acc[mt][j],0,0,0);
                    acc[mt][j] = __builtin_amdgcn_mfma_f32_32x32x16_bf16(ah[mt], bl, acc[mt][j],0,0,0);
                    acc[mt][j] = __builtin_amdgcn_mfma_f32_32x32x16_bf16(ah[mt], bh, acc[mt][j],0,0,0);
                }
            }
        }
    }

    const int p = 2*zt + sg;
    const int zglob = z0 - 1 + p;
    const size_t rowbase = ((size_t)p*64 + yt)*66;
    {
        size_t pbase = (rowbase + (cg?65:0))*128 + 2*lane;
        *(u32*)(h1hi + pbase) = 0u;
        *(u32*)(h1lo + pbase) = 0u;
    }
    const bool zok = ((unsigned)zglob < 64u);
    float bvals[2][16];
    #pragma unroll
    for (int mt=0;mt<2;++mt)
        #pragma unroll
        for (int r=0;r<16;++r)
            bvals[mt][r] = b1[cg*64 + mt*32 + (r&3) + 8*(r>>2) + 4*g];

    #pragma unroll
    for (int j=0;j<2;++j){
        size_t base = (rowbase + j*32 + n + 1)*128 + cg*64;
        #pragma unroll
        for (int mt=0;mt<2;++mt){
            u16 hs[16], ls[16];
            #pragma unroll
            for (int r=0;r<16;++r){
                float v = acc[mt][j][r] + bvals[mt][r];
                v = (zok && v>0.f) ? v : 0.f;
                u16 h = f2bf(v);
                float hf = __uint_as_float(((u32)h)<<16);
                hs[r]=h; ls[r]=f2bf(v-hf);
            }
            #pragma unroll
            for (int q=0;q<4;++q){
                size_t addr = base + mt*32 + q*8 + 4*g;
                uint2 sh, sl;
                sh.x = (u32)hs[4*q]   | ((u32)hs[4*q+1]<<16);
                sh.y = (u32)hs[4*q+2] | ((u32)hs[4*q+3]<<16);
                sl.x = (u32)ls[4*q]   | ((u32)ls[4*q+1]<<16);
                sl.y = (u32)ls[4*q+2] | ((u32)ls[4*q+3]<<16);
                *(uint2*)(h1hi + addr) = sh;
                *(uint2*)(h1lo + addr) = sl;
            }
        }
    }
}

// ---------------- conv2 (MFMA bf16x3) fused with wf-dot + sigmoid -> scores ------
__global__ void __launch_bounds__(256,3) conv2_mfma(
    const u16* __restrict__ h1hi, const u16* __restrict__ h1lo,
    const u16* __restrict__ whi,  const u16* __restrict__ wlo,
    const float* __restrict__ b2, const float* __restrict__ wf,
    const float* __restrict__ bf, float* __restrict__ scores, int z0)
{
    int yt, zt; xcd_decode(blockIdx.x, yt, zt);
    const int t  = threadIdx.x;
    const int lane = t & 63;
    const int w  = t >> 6;
    const int cg = w & 1;
    const int sg = w >> 1;
    const int n  = lane & 31;
    const int g  = lane >> 5;

    __shared__ uint4 sthi[C2_UNITS];
    __shared__ uint4 stlo[C2_UNITS];

    f32x16 acc[2][2];
    #pragma unroll
    for (int a=0;a<2;++a)
        #pragma unroll
        for (int b2_=0;b2_<2;++b2_)
            #pragma unroll
            for (int r=0;r<16;++r) acc[a][b2_][r]=0.f;

    const int aoff_u4 = (cg*64 + n)*2 + g;

    for (int c=0; c<8; ++c){
        __syncthreads();
        for (int u=t; u<C2_UNITS; u+=256){
            int row = u/132, rem = u-row*132;
            int x = rem>>1, gg = rem&1;
            int zr = row/3, yr = row-zr*3;
            int p = 2*zt + zr;
            int y = yt - 1 + yr;
            int pu = (row*66 + x)*2 + (gg ^ ((x>>2)&1));
            uint4 vh; vh.x=vh.y=vh.z=vh.w=0u;
            uint4 vl; vl.x=vl.y=vl.z=vl.w=0u;
            if ((unsigned)y < 64u){
                size_t off = (((size_t)p*64 + y)*66 + x)*128 + c*16 + gg*8;
                vh = *(const uint4*)(h1hi + off);
                vl = *(const uint4*)(h1lo + off);
            }
            sthi[pu]=vh; stlo[pu]=vl;
        }
        __syncthreads();
        for (int tap=0; tap<27; ++tap){
            int dz = tap/9, r9 = tap-dz*9;
            int dy = r9/3, dx = r9-dy*3;
            const uint4* wbh = (const uint4*)whi + (size_t)(tap*8+c)*256 + aoff_u4;
            const uint4* wbl = (const uint4*)wlo + (size_t)(tap*8+c)*256 + aoff_u4;
            s16x8 ah[2], al[2];
            #pragma unroll
            for (int mt=0; mt<2; ++mt){
                uint4 th = wbh[mt*64];
                uint4 tl = wbl[mt*64];
                ah[mt] = *(const s16x8*)&th;
                al[mt] = *(const s16x8*)&tl;
            }
            int rowb = ((sg+dz)*3 + dy)*66;
            #pragma unroll
            for (int j=0;j<2;++j){
                int xpos = j*32 + n + dx;
                int pu = (rowb + xpos)*2 + (g ^ ((xpos>>2)&1));
                uint4 bhq = sthi[pu], blq = stlo[pu];
                s16x8 bh = *(const s16x8*)&bhq;
                s16x8 bl = *(const s16x8*)&blq;
                #pragma unroll
                for (int mt=0; mt<2; ++mt){
                    acc[mt][j] = __builtin_amdgcn_mfma_f32_32x32x16_bf16(al[mt], bh, acc[mt][j],0,0,0);
                    acc[mt][j] = __builtin_amdgcn_mfma_f32_32x32x16_bf16(ah[mt], bl, acc[mt][j],0,0,0);
                    acc[mt][j] = __builtin_amdgcn_mfma_f32_32x32x16_bf16(ah[mt], bh, acc[mt][j],0,0,0);
                }
            }
        }
    }
    __syncthreads();
    float* red = (float*)sthi;
    float b2v[2][16], wfv[2][16];
    #pragma unroll
    for (int mt=0;mt<2;++mt)
        #pragma unroll
        for (int r=0;r<16;++r){
            int co = cg*64 + mt*32 + (r&3) + 8*(r>>2) + 4*g;
            b2v[mt][r]=b2[co]; wfv[mt][r]=wf[co];
        }
    float part[2];
    #pragma unroll
    for (int j=0;j<2;++j){
        float s=0.f;
        #pragma unroll
        for (int mt=0;mt<2;++mt)
            #pragma unroll
            for (int r=0;r<16;++r){
                float v = acc[mt][j][r] + b2v[mt][r];
                v = v>0.f?v:0.f;
                s = fmaf(v, wfv[mt][r], s);
            }
        part[j]=s;
    }
    int sidx0 = sg*64 + n;
    if (cg==0){ red[sidx0]=part[0]; red[sidx0+32]=part[1]; }
    __syncthreads();
    if (cg==1){
        float bfv = bf[0];
        int z = z0 + 2*zt + sg;
        #pragma unroll
        for (int j=0;j<2;++j){
            float tot = red[sidx0 + 32*j] + part[j] + bfv;
            scores[((size_t)z*64 + yt)*64 + j*32 + n] = 1.f/(1.f+expf(-tot));
        }
    }
}

// ---------------- fused x+y 5-tap max pool over one z-plane ----------------------
__global__ void __launch_bounds__(256) pool_xy_k(const float* __restrict__ in, float* __restrict__ out){
    const int plane = blockIdx.x;        // 0..NB*64-1
    __shared__ float sp[64][65];
    const float* src = in + (size_t)plane*G2;
    const int t = threadIdx.x;
    for (int e=t; e<4096; e+=256){
        int y=e>>6, x=e&63;
        float v = src[e];
        if (x>=1)  v=fmaxf(v, src[e-1]);
        if (x>=2)  v=fmaxf(v, src[e-2]);
        if (x<=62) v=fmaxf(v, src[e+1]);
        if (x<=61) v=fmaxf(v, src[e+2]);
        sp[y][x]=v;
    }
    __syncthreads();
    float* dst = out + (size_t)plane*G2;
    for (int e=t; e<4096; e+=256){
        int y=e>>6, x=e&63;
        float v = sp[y][x];
        if (y>=1)  v=fmaxf(v, sp[y-1][x]);
        if (y>=2)  v=fmaxf(v, sp[y-2][x]);
        if (y<=62) v=fmaxf(v, sp[y+1][x]);
        if (y<=61) v=fmaxf(v, sp[y+2][x]);
        dst[e]=v;
    }
}

// ---------------- z-dim 5-tap max pool -------------------------------------------
__global__ void pool1d_k(const float* __restrict__ in, float* __restrict__ out, int sh){
    int i = blockIdx.x*256 + threadIdx.x;
    if (i >= NB*G3) return;
    int p = (i >> sh) & 63;
    int s = 1 << sh;
    float v = in[i];
    if (p >= 1)  v = fmaxf(v, in[i - s]);
    if (p >= 2)  v = fmaxf(v, in[i - 2*s]);
    if (p <= 62) v = fmaxf(v, in[i + s]);
    if (p <= 61) v = fmaxf(v, in[i + 2*s]);
    out[i] = v;
}

__global__ void eq_k(const float* __restrict__ a, const float* __restrict__ b, float* __restrict__ m){
    int i = blockIdx.x*256 + threadIdx.x;
    if (i >= NB*G3) return;
    m[i] = (a[i]==b[i]) ? 1.f : 0.f;
}
__global__ void supp_ss_k(const float* __restrict__ s, float* __restrict__ supp, float* __restrict__ ss){
    int i = blockIdx.x*256 + threadIdx.x;
    if (i >= NB*G3) return;
    bool sp = supp[i] > 0.f;
    supp[i] = sp ? 1.f : 0.f;
    ss[i]   = sp ? 0.f : s[i];
}
__global__ void upd_mask_k(float* __restrict__ mask, const float* __restrict__ ss,
                           const float* __restrict__ mss, const float* __restrict__ supp){
    int i = blockIdx.x*256 + threadIdx.x;
    if (i >= NB*G3) return;
    bool nm = (ss[i]==mss[i]) && (supp[i]==0.f);
    mask[i] = (mask[i]!=0.f || nm) ? 1.f : 0.f;
}

__global__ void init_k(int* cnt){ if (threadIdx.x < NB) cnt[threadIdx.x]=0; }

__global__ void compact_k(const float* __restrict__ mask, const float* __restrict__ s,
                          float* __restrict__ lv, int* __restrict__ li, int* __restrict__ cnt){
    int i = blockIdx.x*256 + threadIdx.x;
    if (i >= NB*G3) return;
    if (mask[i]!=0.f){
        int b = i >> 18;
        int pos = atomicAdd(&cnt[b],1);
        if (pos < CAPN){
            lv[(size_t)b*CAPN+pos] = s[i];
            li[(size_t)b*CAPN+pos] = i & (G3-1);
        }
    }
}

// ---------------- top-k (k=128) ---------------------------------------------------
__global__ void __launch_bounds__(256) topk_k(float* __restrict__ lv, const int* __restrict__ li,
                       const int* __restrict__ cnt, float* __restrict__ tv, int* __restrict__ ti){
    const int b = blockIdx.x;
    const int t = threadIdx.x;
    __shared__ float sv[256]; __shared__ int si[256]; __shared__ int sp[256];
    int n = cnt[b]; if (n > CAPN) n = CAPN;
    float* Lv = lv + (size_t)b*CAPN;
    const int* Li = li + (size_t)b*CAPN;
    for (int r=0; r<TOPKN; ++r){
        float bv = 0.f; int bi = 0x7fffffff; int bp = -1;
        for (int j=t; j<n; j+=256){
            float v = Lv[j];
            int  ix = Li[j];
            if (v > bv || (v == bv && bp >= 0 && ix < bi)) { bv=v; bi=ix; bp=j; }
        }
        sv[t]=bv; si[t]=bi; sp[t]=bp;
        __syncthreads();
        for (int off=128; off>0; off>>=1){
            if (t < off){
                float v2=sv[t+off];
                if (sp[t+off] >= 0 && (sp[t] < 0 || v2 > sv[t] || (v2==sv[t] && si[t+off] < si[t]))){
                    sv[t]=v2; si[t]=si[t+off]; sp[t]=sp[t+off];
                }
            }
            __syncthreads();
        }
        if (t==0){
            if (sp[0] >= 0 && sv[0] > 0.f){
                tv[b*TOPKN+r]=sv[0]; ti[b*TOPKN+r]=si[0];
                Lv[sp[0]] = -1.f;
            } else { tv[b*TOPKN+r]=0.f; ti[b*TOPKN+r]=0; }
        }
        __syncthreads();
    }
}

// ---------------- per-detection bbox+clas heads + decode --------------------------
__global__ void __launch_bounds__(512) perdet_k(
    const float* __restrict__ neck,
    const float* __restrict__ tv, const int* __restrict__ ti,
    const float* __restrict__ bw1, const float* __restrict__ bb1,
    const float* __restrict__ bw2, const float* __restrict__ bb2,
    const float* __restrict__ bwf, const float* __restrict__ bbf,
    const float* __restrict__ lw1, const float* __restrict__ lb1,
    const float* __restrict__ lw2, const float* __restrict__ lb2,
    const float* __restrict__ lwf, const float* __restrict__ lbf,
    float* __restrict__ out)
{
    const int blk = blockIdx.x;
    const int b = blk >> 7, r = blk & 127;
    const int t = threadIdx.x;
    float score = tv[b*TOPKN + r];
    int   idx   = ti[b*TOPKN + r];
    float* orow = out + ((size_t)b*TOPKN + r)*43;
    if (!(score > DET_TH)){
        if (t < 43) orow[t] = 0.f;
        return;
    }
    const int iz = idx >> 12, iy = (idx>>6)&63, ix = idx&63;

    __shared__ float pin[CIN][125];
    __shared__ float h1s[27][HIDC];
    __shared__ float h2s[HIDC];
    __shared__ float raws[7+NCLASS];

    const float* inb = neck + (size_t)b*CIN*G3;
    for (int e=t; e<CIN*125; e+=512){
        int ci=e/125, q=e-ci*125;
        int pz=q/25, py=(q/5)%5, px=q%5;
        int gz=iz-2+pz, gy=iy-2+py, gx=ix-2+px;
        float v=0.f;
        if ((unsigned)gz<64u && (unsigned)gy<64u && (unsigned)gx<64u)
            v = inb[(size_t)ci*G3 + (size_t)gz*G2 + gy*Gd + gx];
        pin[ci][q]=v;
    }
    __syncthreads();

    for (int head=0; head<2; ++head){
        const float* w1 = head? lw1 : bw1;
        const float* b1 = head? lb1 : bb1;
        const float* w2 = head? lw2 : bw2;
        const float* b2 = head? lb2 : bb2;
        const float* wf = head? lwf : bwf;
        const float* bf = head? lbf : bbf;
        const int fdim  = head? NCLASS : 7;

        for (int e=t; e<27*HIDC; e+=512){
            int co = e & 127, pos = e >> 7;
            int pdz=pos/9, pdy=(pos/3)%3, pdx=pos%3;
            int gz=iz-1+pdz, gy=iy-1+pdy, gx=ix-1+pdx;
            float acc = 0.f;
            if ((unsigned)gz<64u && (unsigned)gy<64u && (unsigned)gx<64u){
                acc = b1[co];
                const float* wco = w1 + (size_t)co*CIN*27;
                for (int ci=0; ci<CIN; ++ci){
                    const float* pr = pin[ci];
                    const float* wr = wco + ci*27;
                    #pragma unroll
                    for (int tz=0;tz<3;++tz)
                        #pragma unroll
                        for (int ty=0;ty<3;++ty)
                            #pragma unroll
                            for (int tx=0;tx<3;++tx)
                                acc = fmaf(pr[(pdz+tz)*25+(pdy+ty)*5+(pdx+tx)],
                                           wr[(tz*3+ty)*3+tx], acc);
                }
                acc = acc>0.f ? acc : 0.f;
            }
            h1s[pos][co]=acc;
        }
        __syncthreads();

        if (t < HIDC){
            float acc = b2[t];
            const float* wco = w2 + (size_t)t*HIDC*27;
            for (int pos=0; pos<27; ++pos){
                const float* hr = h1s[pos];
                for (int ci=0; ci<HIDC; ++ci)
                    acc = fmaf(hr[ci], wco[ci*27+pos], acc);
            }
            h2s[t] = acc>0.f ? acc : 0.f;
        }
        __syncthreads();

        if (t < fdim){
            float acc = bf[t];
            const float* wr = wf + t*HIDC;
            for (int ci=0; ci<HIDC; ++ci) acc = fmaf(h2s[ci], wr[ci], acc);
            raws[(head?7:0)+t] = acc;
        }
        __syncthreads();
    }

    if (t==0){
        const float vx = (float)(6.4/64.0);
        float cx = -3.2f + ((float)ix + 0.5f)*vx;
        float cy = -3.2f + ((float)iy + 0.5f)*vx;
        float cz = -3.2f + ((float)iz + 0.5f)*vx;
        float sx = 5.9f*(1.f/(1.f+expf(-raws[0]))) + 0.1f;
        float sy = 5.9f*(1.f/(1.f+expf(-raws[1]))) + 0.1f;
        float sz = 5.9f*(1.f/(1.f+expf(-raws[2]))) + 0.1f;
        float ox = 0.2f*tanhf(raws[3]);
        float oy = 0.2f*tanhf(raws[4]);
        float oz = 0.2f*tanhf(raws[5]);
        float yw = 1.6f*tanhf(raws[6]);
        orow[0]=cx+ox; orow[1]=cy+oy; orow[2]=cz+oz;
        orow[3]=sx; orow[4]=sy; orow[5]=sz;
        orow[6]=yw; orow[7]=score; orow[8]=1.f;
        float mx = raws[7];
        #pragma unroll
        for (int i=1;i<NCLASS;++i) mx = fmaxf(mx, raws[7+i]);
        float ev[NCLASS]; float sum=0.f;
        #pragma unroll
        for (int i=0;i<NCLASS;++i){ ev[i]=expf(raws[7+i]-mx); sum+=ev[i]; }
        float inv = 1.f/sum;
        #pragma unroll
        for (int i=0;i<NCLASS;++i) orow[9+i] = ev[i]*inv;
    }
}

extern "C" void kernel_launch(void* const* d_in, const int* in_sizes, int n_in,
                              void* d_out, int out_size, void* d_ws, size_t ws_size,
                              hipStream_t stream)
{
    (void)in_sizes; (void)n_in; (void)out_size;
    const float* neck = (const float*)d_in[0];
    const float* ce_w1=(const float*)d_in[1],  *ce_b1=(const float*)d_in[2];
    const float* ce_w2=(const float*)d_in[3],  *ce_b2=(const float*)d_in[4];
    const float* ce_wf=(const float*)d_in[5],  *ce_bf=(const float*)d_in[6];
    const float* bb_w1=(const float*)d_in[7],  *bb_b1=(const float*)d_in[8];
    const float* bb_w2=(const float*)d_in[9],  *bb_b2=(const float*)d_in[10];
    const float* bb_wf=(const float*)d_in[11], *bb_bf=(const float*)d_in[12];
    const float* cl_w1=(const float*)d_in[13], *cl_b1=(const float*)d_in[14];
    const float* cl_w2=(const float*)d_in[15], *cl_b2=(const float*)d_in[16];
    const float* cl_wf=(const float*)d_in[17], *cl_bf=(const float*)d_in[18];
    float* out = (float*)d_out;
    char* ws = (char*)d_ws;

    float* scores=(float*)(ws + 0);
    float* tA    =(float*)(ws + (2u<<20));
    float* tB    =(float*)(ws + (4u<<20));
    float* bufM  =(float*)(ws + (6u<<20));
    float* mask  =(float*)(ws + (8u<<20));
    float* supp  =(float*)(ws + (10u<<20));
    float* ssb   =(float*)(ws + (12u<<20));
    float* lv    =(float*)(ws + (14u<<20));
    int*   li    =(int*)  (ws + (14u<<20) + (512u<<10));
    float* tv    =(float*)(ws + (15u<<20));
    int*   ti    =(int*)  (ws + (15u<<20) + 4096);
    int*   cnt   =(int*)  (ws + (15u<<20) + 8192);
    u16*   whi1  =(u16*)  (ws + (15u<<20) + 16384);
    u16*   wlo1  =(u16*)  (ws + (15u<<20) + (512u<<10));
    u16*   whi2  =(u16*)  (ws + (16u<<20));
    u16*   wlo2  =(u16*)  (ws + (17u<<20));
    u16*   nbhi  =(u16*)  (ws + (18u<<20));
    u16*   nblo  =(u16*)  (ws + (51u<<20));
    u16*   h1hi  =(u16*)  (ws + (84u<<20));

    const size_t plane_u16 = (size_t)64*66*128;
    const size_t plane2_b  = plane_u16*2*2;
    const size_t fixedb = 84u<<20;
    int Tz = 4;
    if      (ws_size >= fixedb + 66*plane2_b) Tz = 64;
    else if (ws_size >= fixedb + 34*plane2_b) Tz = 32;
    else if (ws_size >= fixedb + 18*plane2_b) Tz = 16;
    else if (ws_size >= fixedb + 10*plane2_b) Tz = 8;
    const int nplanes = Tz + 2;
    u16* h1lo = h1hi + (size_t)nplanes*plane_u16;

    init_k<<<1, 64, 0, stream>>>(cnt);
    repack1b_k<<<(27*128*64 +255)/256, 256, 0, stream>>>(ce_w1, whi1, wlo1);
    repack2_k<<<(27*128*128+255)/256, 256, 0, stream>>>(ce_w2, whi2, wlo2);

    for (int b=0; b<NB; ++b){
        const float* inb = neck + (size_t)b*CIN*G3;
        float* scb = scores + (size_t)b*G3;
        nbconv_k<<<4096, 256, 0, stream>>>(inb, nbhi, nblo);
        for (int z0=0; z0<Gd; z0+=Tz){
            conv1_mfma<<<64*(nplanes/2), 256, 0, stream>>>(nbhi, nblo, whi1, wlo1, ce_b1, h1hi, h1lo, z0);
            conv2_mfma<<<64*(Tz/2),      256, 0, stream>>>(h1hi, h1lo, whi2, wlo2, ce_b2, ce_wf, ce_bf, scb, z0);
        }
    }

    const int n = NB*G3, nb = n/256;
    // maxpool3d = fused xy-pool + z-pool
    #define POOL3(SRC, DST) \
        pool_xy_k<<<NB*64,256,0,stream>>>((SRC), tA); \
        pool1d_k<<<nb,256,0,stream>>>(tA, (DST), 12);

    POOL3(scores, bufM);
    eq_k<<<nb,256,0,stream>>>(scores, bufM, mask);
    for (int it=0; it<2; ++it){
        POOL3(mask, supp);
        supp_ss_k<<<nb,256,0,stream>>>(scores, supp, ssb);
        POOL3(ssb, bufM);
        upd_mask_k<<<nb,256,0,stream>>>(mask, ssb, bufM, supp);
    }
    #undef POOL3

    compact_k<<<nb,256,0,stream>>>(mask, scores, lv, li, cnt);
    topk_k<<<NB,256,0,stream>>>(lv, li, cnt, tv, ti);
    perdet_k<<<NB*TOPKN,512,0,stream>>>(neck, tv, ti,
        bb_w1,bb_b1,bb_w2,bb_b2,bb_wf,bb_bf,
        cl_w1,cl_b1,cl_w2,cl_b2,cl_wf,cl_bf, out);
}

// Round 5
// 1998.802 us; speedup vs baseline: 4.5219x; 1.3816x over previous
//
#include <hip/hip_runtime.h>
#include <math.h>

#define Gd 64
#define G2 4096
#define G3 262144
#define CIN 64
#define HIDC 128
#define NB 2
#define TOPKN 128
#define NCLASS 34
#define CAPN 65536
#define DET_TH 0.2f

typedef unsigned short u16;
typedef unsigned int u32;
typedef unsigned long long u64;
typedef float f32x16 __attribute__((ext_vector_type(16)));
typedef short s16x8  __attribute__((ext_vector_type(8)));

__device__ __forceinline__ u16 f2bf(float x){
    u32 u = __float_as_uint(x);
    u32 r = u + 0x7fffu + ((u>>16)&1u);
    return (u16)(r>>16);
}

// ---------------- weight repack conv1 (bf16 split) -------------------------------
__global__ void repack1b_k(const float* __restrict__ w, u16* __restrict__ whi, u16* __restrict__ wlo){
    int i = blockIdx.x*256 + threadIdx.x;
    if (i >= 27*128*64) return;
    int tap = i >> 13;
    int r   = i & 8191;
    int co  = r >> 6;
    int ci  = r & 63;
    float v = w[((size_t)co*64 + ci)*27 + tap];
    u16 h = f2bf(v);
    float hf = __uint_as_float(((u32)h)<<16);
    u16 l = f2bf(v - hf);
    size_t dst = ((size_t)(tap*4 + (ci>>4))*128 + co)*16 + (ci&15);
    whi[dst] = h; wlo[dst] = l;
}

// ---------------- weight repack conv2 (bf16 split) -------------------------------
__global__ void repack2_k(const float* __restrict__ w, u16* __restrict__ whi, u16* __restrict__ wlo){
    int i = blockIdx.x*256 + threadIdx.x;
    if (i >= 27*128*128) return;
    int tap = i >> 14;
    int r   = i & 16383;
    int co  = r >> 7;
    int ci  = r & 127;
    float v = w[((size_t)co*128 + ci)*27 + tap];
    u16 h = f2bf(v);
    float hf = __uint_as_float(((u32)h)<<16);
    u16 l = f2bf(v - hf);
    size_t dst = ((size_t)(tap*8 + (ci>>4))*128 + co)*16 + (ci&15);
    whi[dst] = h; wlo[dst] = l;
}

// ---------------- neck -> channel-last bf16 hi/lo --------------------------------
__global__ void __launch_bounds__(256) nbconv_k(const float* __restrict__ in,
                                                u16* __restrict__ nhi, u16* __restrict__ nlo){
    const int zy = blockIdx.x;
    const int t  = threadIdx.x;
    __shared__ u16 shi[64][68];
    __shared__ u16 slo[64][68];
    const int x = t & 63, wv = t >> 6;
    const float* src = in + (size_t)zy*64;
    #pragma unroll
    for (int r=0;r<16;++r){
        int ci = wv*16 + r;
        float v = src[(size_t)ci*G3 + x];
        u16 h = f2bf(v);
        float hf = __uint_as_float(((u32)h)<<16);
        shi[x][ci]=h; slo[x][ci]=f2bf(v-hf);
    }
    __syncthreads();
    const size_t obase = (size_t)zy*66*64;
    for (int e=t; e<64*32; e+=256){
        int xx=e>>5, cp=e&31;
        *(u32*)(nhi + obase + (size_t)(xx+1)*64 + 2*cp) = *(const u32*)&shi[xx][2*cp];
        *(u32*)(nlo + obase + (size_t)(xx+1)*64 + 2*cp) = *(const u32*)&slo[xx][2*cp];
    }
    if (t < 64){
        int px = (t<32)?0:65; int cp=t&31;
        *(u32*)(nhi + obase + (size_t)px*64 + 2*cp) = 0u;
        *(u32*)(nlo + obase + (size_t)px*64 + 2*cp) = 0u;
    }
}

#define C2_UNITS (12*66*2)   // 1584 16B-units per array

// XCD-aware decode: xcd = b&7 owns yt band [xcd*8, xcd*8+8), sweeps zt ascending.
__device__ __forceinline__ void xcd_decode(int b, int& yt, int& zt){
    int xcd = b & 7, j = b >> 3;
    yt = xcd*8 + (j & 7);
    zt = j >> 3;
}

// ---------------- conv1 (MFMA bf16x3): nb(64ci) -> h1(128co) bf16 hi/lo ----------
__global__ void __launch_bounds__(256,3) conv1_mfma(
    const u16* __restrict__ nhi, const u16* __restrict__ nlo,
    const u16* __restrict__ whi, const u16* __restrict__ wlo,
    const float* __restrict__ b1,
    u16* __restrict__ h1hi, u16* __restrict__ h1lo, int z0)
{
    int yt, zt; xcd_decode(blockIdx.x, yt, zt);
    const int t  = threadIdx.x;
    const int lane = t & 63;
    const int w  = t >> 6;
    const int cg = w & 1;
    const int sg = w >> 1;
    const int n  = lane & 31;
    const int g  = lane >> 5;

    __shared__ uint4 sthi[C2_UNITS];
    __shared__ uint4 stlo[C2_UNITS];

    f32x16 acc[2][2];
    #pragma unroll
    for (int a=0;a<2;++a)
        #pragma unroll
        for (int b2_=0;b2_<2;++b2_)
            #pragma unroll
            for (int r=0;r<16;++r) acc[a][b2_][r]=0.f;

    const int aoff_u4 = (cg*64 + n)*2 + g;

    for (int c=0; c<4; ++c){
        __syncthreads();
        for (int u=t; u<C2_UNITS; u+=256){
            int row = u/132, rem = u-row*132;
            int x = rem>>1, gg = rem&1;
            int zr = row/3, yr = row-zr*3;
            int zin = z0 - 2 + 2*zt + zr;
            int y = yt - 1 + yr;
            int pu = (row*66 + x)*2 + (gg ^ ((x>>2)&1));
            uint4 vh; vh.x=vh.y=vh.z=vh.w=0u;
            uint4 vl; vl.x=vl.y=vl.z=vl.w=0u;
            if ((unsigned)y < 64u && (unsigned)zin < 64u){
                size_t off = (((size_t)zin*64 + y)*66 + x)*64 + c*16 + gg*8;
                vh = *(const uint4*)(nhi + off);
                vl = *(const uint4*)(nlo + off);
            }
            sthi[pu]=vh; stlo[pu]=vl;
        }
        __syncthreads();
        for (int tap=0; tap<27; ++tap){
            int dz = tap/9, r9 = tap-dz*9;
            int dy = r9/3, dx = r9-dy*3;
            const uint4* wbh = (const uint4*)whi + (size_t)(tap*4+c)*256 + aoff_u4;
            const uint4* wbl = (const uint4*)wlo + (size_t)(tap*4+c)*256 + aoff_u4;
            s16x8 ah[2], al[2];
            #pragma unroll
            for (int mt=0; mt<2; ++mt){
                uint4 th = wbh[mt*64];
                uint4 tl = wbl[mt*64];
                ah[mt] = *(const s16x8*)&th;
                al[mt] = *(const s16x8*)&tl;
            }
            int rowb = ((sg+dz)*3 + dy)*66;
            #pragma unroll
            for (int j=0;j<2;++j){
                int xpos = j*32 + n + dx;
                int pu = (rowb + xpos)*2 + (g ^ ((xpos>>2)&1));
                uint4 bhq = sthi[pu], blq = stlo[pu];
                s16x8 bh = *(const s16x8*)&bhq;
                s16x8 bl = *(const s16x8*)&blq;
                #pragma unroll
                for (int mt=0; mt<2; ++mt){
                    acc[mt][j] = __builtin_amdgcn_mfma_f32_32x32x16_bf16(al[mt], bh, acc[mt][j],0,0,0);
                    acc[mt][j] = __builtin_amdgcn_mfma_f32_32x32x16_bf16(ah[mt], bl, acc[mt][j],0,0,0);
                    acc[mt][j] = __builtin_amdgcn_mfma_f32_32x32x16_bf16(ah[mt], bh, acc[mt][j],0,0,0);
                }
            }
        }
    }

    const int p = 2*zt + sg;
    const int zglob = z0 - 1 + p;
    const size_t rowbase = ((size_t)p*64 + yt)*66;
    {
        size_t pbase = (rowbase + (cg?65:0))*128 + 2*lane;
        *(u32*)(h1hi + pbase) = 0u;
        *(u32*)(h1lo + pbase) = 0u;
    }
    const bool zok = ((unsigned)zglob < 64u);
    float bvals[2][16];
    #pragma unroll
    for (int mt=0;mt<2;++mt)
        #pragma unroll
        for (int r=0;r<16;++r)
            bvals[mt][r] = b1[cg*64 + mt*32 + (r&3) + 8*(r>>2) + 4*g];

    #pragma unroll
    for (int j=0;j<2;++j){
        size_t base = (rowbase + j*32 + n + 1)*128 + cg*64;
        #pragma unroll
        for (int mt=0;mt<2;++mt){
            u16 hs[16], ls[16];
            #pragma unroll
            for (int r=0;r<16;++r){
                float v = acc[mt][j][r] + bvals[mt][r];
                v = (zok && v>0.f) ? v : 0.f;
                u16 h = f2bf(v);
                float hf = __uint_as_float(((u32)h)<<16);
                hs[r]=h; ls[r]=f2bf(v-hf);
            }
            #pragma unroll
            for (int q=0;q<4;++q){
                size_t addr = base + mt*32 + q*8 + 4*g;
                uint2 sh, sl;
                sh.x = (u32)hs[4*q]   | ((u32)hs[4*q+1]<<16);
                sh.y = (u32)hs[4*q+2] | ((u32)hs[4*q+3]<<16);
                sl.x = (u32)ls[4*q]   | ((u32)ls[4*q+1]<<16);
                sl.y = (u32)ls[4*q+2] | ((u32)ls[4*q+3]<<16);
                *(uint2*)(h1hi + addr) = sh;
                *(uint2*)(h1lo + addr) = sl;
            }
        }
    }
}

// ---------------- conv2 (MFMA bf16x3) fused with wf-dot + sigmoid -> scores ------
__global__ void __launch_bounds__(256,3) conv2_mfma(
    const u16* __restrict__ h1hi, const u16* __restrict__ h1lo,
    const u16* __restrict__ whi,  const u16* __restrict__ wlo,
    const float* __restrict__ b2, const float* __restrict__ wf,
    const float* __restrict__ bf, float* __restrict__ scores, int z0)
{
    int yt, zt; xcd_decode(blockIdx.x, yt, zt);
    const int t  = threadIdx.x;
    const int lane = t & 63;
    const int w  = t >> 6;
    const int cg = w & 1;
    const int sg = w >> 1;
    const int n  = lane & 31;
    const int g  = lane >> 5;

    __shared__ uint4 sthi[C2_UNITS];
    __shared__ uint4 stlo[C2_UNITS];

    f32x16 acc[2][2];
    #pragma unroll
    for (int a=0;a<2;++a)
        #pragma unroll
        for (int b2_=0;b2_<2;++b2_)
            #pragma unroll
            for (int r=0;r<16;++r) acc[a][b2_][r]=0.f;

    const int aoff_u4 = (cg*64 + n)*2 + g;

    for (int c=0; c<8; ++c){
        __syncthreads();
        for (int u=t; u<C2_UNITS; u+=256){
            int row = u/132, rem = u-row*132;
            int x = rem>>1, gg = rem&1;
            int zr = row/3, yr = row-zr*3;
            int p = 2*zt + zr;
            int y = yt - 1 + yr;
            int pu = (row*66 + x)*2 + (gg ^ ((x>>2)&1));
            uint4 vh; vh.x=vh.y=vh.z=vh.w=0u;
            uint4 vl; vl.x=vl.y=vl.z=vl.w=0u;
            if ((unsigned)y < 64u){
                size_t off = (((size_t)p*64 + y)*66 + x)*128 + c*16 + gg*8;
                vh = *(const uint4*)(h1hi + off);
                vl = *(const uint4*)(h1lo + off);
            }
            sthi[pu]=vh; stlo[pu]=vl;
        }
        __syncthreads();
        for (int tap=0; tap<27; ++tap){
            int dz = tap/9, r9 = tap-dz*9;
            int dy = r9/3, dx = r9-dy*3;
            const uint4* wbh = (const uint4*)whi + (size_t)(tap*8+c)*256 + aoff_u4;
            const uint4* wbl = (const uint4*)wlo + (size_t)(tap*8+c)*256 + aoff_u4;
            s16x8 ah[2], al[2];
            #pragma unroll
            for (int mt=0; mt<2; ++mt){
                uint4 th = wbh[mt*64];
                uint4 tl = wbl[mt*64];
                ah[mt] = *(const s16x8*)&th;
                al[mt] = *(const s16x8*)&tl;
            }
            int rowb = ((sg+dz)*3 + dy)*66;
            #pragma unroll
            for (int j=0;j<2;++j){
                int xpos = j*32 + n + dx;
                int pu = (rowb + xpos)*2 + (g ^ ((xpos>>2)&1));
                uint4 bhq = sthi[pu], blq = stlo[pu];
                s16x8 bh = *(const s16x8*)&bhq;
                s16x8 bl = *(const s16x8*)&blq;
                #pragma unroll
                for (int mt=0; mt<2; ++mt){
                    acc[mt][j] = __builtin_amdgcn_mfma_f32_32x32x16_bf16(al[mt], bh, acc[mt][j],0,0,0);
                    acc[mt][j] = __builtin_amdgcn_mfma_f32_32x32x16_bf16(ah[mt], bl, acc[mt][j],0,0,0);
                    acc[mt][j] = __builtin_amdgcn_mfma_f32_32x32x16_bf16(ah[mt], bh, acc[mt][j],0,0,0);
                }
            }
        }
    }
    __syncthreads();
    float* red = (float*)sthi;
    float b2v[2][16], wfv[2][16];
    #pragma unroll
    for (int mt=0;mt<2;++mt)
        #pragma unroll
        for (int r=0;r<16;++r){
            int co = cg*64 + mt*32 + (r&3) + 8*(r>>2) + 4*g;
            b2v[mt][r]=b2[co]; wfv[mt][r]=wf[co];
        }
    float part[2];
    #pragma unroll
    for (int j=0;j<2;++j){
        float s=0.f;
        #pragma unroll
        for (int mt=0;mt<2;++mt)
            #pragma unroll
            for (int r=0;r<16;++r){
                float v = acc[mt][j][r] + b2v[mt][r];
                v = v>0.f?v:0.f;
                s = fmaf(v, wfv[mt][r], s);
            }
        part[j]=s;
    }
    int sidx0 = sg*64 + n;
    if (cg==0){ red[sidx0]=part[0]; red[sidx0+32]=part[1]; }
    __syncthreads();
    if (cg==1){
        float bfv = bf[0];
        int z = z0 + 2*zt + sg;
        #pragma unroll
        for (int j=0;j<2;++j){
            float tot = red[sidx0 + 32*j] + part[j] + bfv;
            scores[((size_t)z*64 + yt)*64 + j*32 + n] = 1.f/(1.f+expf(-tot));
        }
    }
}

// ---------------- fused x+y 5-tap max pool over one z-plane ----------------------
__global__ void __launch_bounds__(256) pool_xy_k(const float* __restrict__ in, float* __restrict__ out){
    const int plane = blockIdx.x;        // 0..NB*64-1
    __shared__ float sp[64][65];
    const float* src = in + (size_t)plane*G2;
    const int t = threadIdx.x;
    for (int e=t; e<4096; e+=256){
        int y=e>>6, x=e&63;
        float v = src[e];
        if (x>=1)  v=fmaxf(v, src[e-1]);
        if (x>=2)  v=fmaxf(v, src[e-2]);
        if (x<=62) v=fmaxf(v, src[e+1]);
        if (x<=61) v=fmaxf(v, src[e+2]);
        sp[y][x]=v;
    }
    __syncthreads();
    float* dst = out + (size_t)plane*G2;
    for (int e=t; e<4096; e+=256){
        int y=e>>6, x=e&63;
        float v = sp[y][x];
        if (y>=1)  v=fmaxf(v, sp[y-1][x]);
        if (y>=2)  v=fmaxf(v, sp[y-2][x]);
        if (y<=62) v=fmaxf(v, sp[y+1][x]);
        if (y<=61) v=fmaxf(v, sp[y+2][x]);
        dst[e]=v;
    }
}

__device__ __forceinline__ float zpool5(const float* __restrict__ a, int i){
    int p = (i >> 12) & 63;
    float v = a[i];
    if (p >= 1)  v = fmaxf(v, a[i - 4096]);
    if (p >= 2)  v = fmaxf(v, a[i - 8192]);
    if (p <= 62) v = fmaxf(v, a[i + 4096]);
    if (p <= 61) v = fmaxf(v, a[i + 8192]);
    return v;
}

// mask = (scores == pool3d(scores))
__global__ void poolz_eq_k(const float* __restrict__ tA, const float* __restrict__ scores,
                           float* __restrict__ mask){
    int i = blockIdx.x*256 + threadIdx.x;
    if (i >= NB*G3) return;
    mask[i] = (scores[i] == zpool5(tA, i)) ? 1.f : 0.f;
}
// supp = pool3d(mask) > 0 ; ss = supp?0:scores
__global__ void poolz_supp_k(const float* __restrict__ tA, const float* __restrict__ scores,
                             float* __restrict__ supp, float* __restrict__ ss){
    int i = blockIdx.x*256 + threadIdx.x;
    if (i >= NB*G3) return;
    bool sp = zpool5(tA, i) > 0.f;
    supp[i] = sp ? 1.f : 0.f;
    ss[i]   = sp ? 0.f : scores[i];
}
// mask |= (ss == pool3d(ss)) & ~supp
__global__ void poolz_upd_k(const float* __restrict__ tA, const float* __restrict__ ss,
                            const float* __restrict__ supp, float* __restrict__ mask){
    int i = blockIdx.x*256 + threadIdx.x;
    if (i >= NB*G3) return;
    bool nm = (ss[i] == zpool5(tA, i)) && (supp[i] == 0.f);
    mask[i] = (mask[i] != 0.f || nm) ? 1.f : 0.f;
}

__global__ void init_k(int* cnt){ if (threadIdx.x < NB) cnt[threadIdx.x]=0; }

// compact: only candidates that can produce valid rows (score > DET_TH)
__global__ void compact_k(const float* __restrict__ mask, const float* __restrict__ s,
                          float* __restrict__ lv, int* __restrict__ li, int* __restrict__ cnt){
    int i = blockIdx.x*256 + threadIdx.x;
    if (i >= NB*G3) return;
    if (mask[i]!=0.f && s[i] > DET_TH){
        int b = i >> 18;
        int pos = atomicAdd(&cnt[b],1);
        if (pos < CAPN){
            lv[(size_t)b*CAPN+pos] = s[i];
            li[(size_t)b*CAPN+pos] = i & (G3-1);
        }
    }
}

// ---------------- top-k via bitonic sort of packed (score,~idx) keys -------------
// key = (float_bits(score)<<32) | ~idx : descending key = (score desc, idx asc).
__device__ __forceinline__ void bitonic2048_desc(u64* sk, int t){
    for (int k=2; k<=2048; k<<=1){
        for (int j=k>>1; j>0; j>>=1){
            #pragma unroll 4
            for (int i=t; i<2048; i+=256){
                int x = i ^ j;
                if (x > i){
                    bool dirDesc = ((i & k) == 0);
                    u64 a = sk[i], b = sk[x];
                    bool sw = dirDesc ? (a < b) : (a > b);
                    if (sw){ sk[i]=b; sk[x]=a; }
                }
            }
            __syncthreads();
        }
    }
}

__global__ void __launch_bounds__(256) topsort_k(const float* __restrict__ lv, const int* __restrict__ li,
                        const int* __restrict__ cnt, float* __restrict__ tv, int* __restrict__ ti){
    const int b = blockIdx.x;
    const int t = threadIdx.x;
    __shared__ u64 sk[2048];
    int n = cnt[b]; if (n > CAPN) n = CAPN;
    const float* Lv = lv + (size_t)b*CAPN;
    const int*   Li = li + (size_t)b*CAPN;

    for (int e=t; e<2048; e+=256){
        u64 key = 0ull;
        if (e < n)
            key = ((u64)__float_as_uint(Lv[e])<<32) | (u32)(~Li[e]);
        sk[e] = key;
    }
    int processed = n < 2048 ? n : 2048;
    __syncthreads();
    bitonic2048_desc(sk, t);
    while (processed < n){
        int chunk = n - processed; if (chunk > 1920) chunk = 1920;
        for (int e=t; e<1920; e+=256){
            u64 key = 0ull;
            if (e < chunk)
                key = ((u64)__float_as_uint(Lv[processed+e])<<32) | (u32)(~Li[processed+e]);
            sk[128+e] = key;
        }
        processed += chunk;
        __syncthreads();
        bitonic2048_desc(sk, t);
    }
    if (t < TOPKN){
        u64 key = sk[t];
        if (key){
            tv[b*TOPKN+t] = __uint_as_float((u32)(key>>32));
            ti[b*TOPKN+t] = (int)(~(u32)key);
        } else {
            tv[b*TOPKN+t] = 0.f;
            ti[b*TOPKN+t] = 0;
        }
    }
}

// ---------------- per-detection bbox+clas heads + decode --------------------------
__global__ void __launch_bounds__(512) perdet_k(
    const float* __restrict__ neck,
    const float* __restrict__ tv, const int* __restrict__ ti,
    const float* __restrict__ bw1, const float* __restrict__ bb1,
    const float* __restrict__ bw2, const float* __restrict__ bb2,
    const float* __restrict__ bwf, const float* __restrict__ bbf,
    const float* __restrict__ lw1, const float* __restrict__ lb1,
    const float* __restrict__ lw2, const float* __restrict__ lb2,
    const float* __restrict__ lwf, const float* __restrict__ lbf,
    float* __restrict__ out)
{
    const int blk = blockIdx.x;
    const int b = blk >> 7, r = blk & 127;
    const int t = threadIdx.x;
    float score = tv[b*TOPKN + r];
    int   idx   = ti[b*TOPKN + r];
    float* orow = out + ((size_t)b*TOPKN + r)*43;
    if (!(score > DET_TH)){
        if (t < 43) orow[t] = 0.f;
        return;
    }
    const int iz = idx >> 12, iy = (idx>>6)&63, ix = idx&63;

    __shared__ float pin[CIN][125];
    __shared__ float h1s[27][HIDC];
    __shared__ float h2s[HIDC];
    __shared__ float raws[7+NCLASS];

    const float* inb = neck + (size_t)b*CIN*G3;
    for (int e=t; e<CIN*125; e+=512){
        int ci=e/125, q=e-ci*125;
        int pz=q/25, py=(q/5)%5, px=q%5;
        int gz=iz-2+pz, gy=iy-2+py, gx=ix-2+px;
        float v=0.f;
        if ((unsigned)gz<64u && (unsigned)gy<64u && (unsigned)gx<64u)
            v = inb[(size_t)ci*G3 + (size_t)gz*G2 + gy*Gd + gx];
        pin[ci][q]=v;
    }
    __syncthreads();

    for (int head=0; head<2; ++head){
        const float* w1 = head? lw1 : bw1;
        const float* b1 = head? lb1 : bb1;
        const float* w2 = head? lw2 : bw2;
        const float* b2 = head? lb2 : bb2;
        const float* wf = head? lwf : bwf;
        const float* bf = head? lbf : bbf;
        const int fdim  = head? NCLASS : 7;

        for (int e=t; e<27*HIDC; e+=512){
            int co = e & 127, pos = e >> 7;
            int pdz=pos/9, pdy=(pos/3)%3, pdx=pos%3;
            int gz=iz-1+pdz, gy=iy-1+pdy, gx=ix-1+pdx;
            float acc = 0.f;
            if ((unsigned)gz<64u && (unsigned)gy<64u && (unsigned)gx<64u){
                acc = b1[co];
                const float* wco = w1 + (size_t)co*CIN*27;
                for (int ci=0; ci<CIN; ++ci){
                    const float* pr = pin[ci];
                    const float* wr = wco + ci*27;
                    #pragma unroll
                    for (int tz=0;tz<3;++tz)
                        #pragma unroll
                        for (int ty=0;ty<3;++ty)
                            #pragma unroll
                            for (int tx=0;tx<3;++tx)
                                acc = fmaf(pr[(pdz+tz)*25+(pdy+ty)*5+(pdx+tx)],
                                           wr[(tz*3+ty)*3+tx], acc);
                }
                acc = acc>0.f ? acc : 0.f;
            }
            h1s[pos][co]=acc;
        }
        __syncthreads();

        if (t < HIDC){
            float acc = b2[t];
            const float* wco = w2 + (size_t)t*HIDC*27;
            for (int pos=0; pos<27; ++pos){
                const float* hr = h1s[pos];
                for (int ci=0; ci<HIDC; ++ci)
                    acc = fmaf(hr[ci], wco[ci*27+pos], acc);
            }
            h2s[t] = acc>0.f ? acc : 0.f;
        }
        __syncthreads();

        if (t < fdim){
            float acc = bf[t];
            const float* wr = wf + t*HIDC;
            for (int ci=0; ci<HIDC; ++ci) acc = fmaf(h2s[ci], wr[ci], acc);
            raws[(head?7:0)+t] = acc;
        }
        __syncthreads();
    }

    if (t==0){
        const float vx = (float)(6.4/64.0);
        float cx = -3.2f + ((float)ix + 0.5f)*vx;
        float cy = -3.2f + ((float)iy + 0.5f)*vx;
        float cz = -3.2f + ((float)iz + 0.5f)*vx;
        float sx = 5.9f*(1.f/(1.f+expf(-raws[0]))) + 0.1f;
        float sy = 5.9f*(1.f/(1.f+expf(-raws[1]))) + 0.1f;
        float sz = 5.9f*(1.f/(1.f+expf(-raws[2]))) + 0.1f;
        float ox = 0.2f*tanhf(raws[3]);
        float oy = 0.2f*tanhf(raws[4]);
        float oz = 0.2f*tanhf(raws[5]);
        float yw = 1.6f*tanhf(raws[6]);
        orow[0]=cx+ox; orow[1]=cy+oy; orow[2]=cz+oz;
        orow[3]=sx; orow[4]=sy; orow[5]=sz;
        orow[6]=yw; orow[7]=score; orow[8]=1.f;
        float mx = raws[7];
        #pragma unroll
        for (int i=1;i<NCLASS;++i) mx = fmaxf(mx, raws[7+i]);
        float ev[NCLASS]; float sum=0.f;
        #pragma unroll
        for (int i=0;i<NCLASS;++i){ ev[i]=expf(raws[7+i]-mx); sum+=ev[i]; }
        float inv = 1.f/sum;
        #pragma unroll
        for (int i=0;i<NCLASS;++i) orow[9+i] = ev[i]*inv;
    }
}

extern "C" void kernel_launch(void* const* d_in, const int* in_sizes, int n_in,
                              void* d_out, int out_size, void* d_ws, size_t ws_size,
                              hipStream_t stream)
{
    (void)in_sizes; (void)n_in; (void)out_size;
    const float* neck = (const float*)d_in[0];
    const float* ce_w1=(const float*)d_in[1],  *ce_b1=(const float*)d_in[2];
    const float* ce_w2=(const float*)d_in[3],  *ce_b2=(const float*)d_in[4];
    const float* ce_wf=(const float*)d_in[5],  *ce_bf=(const float*)d_in[6];
    const float* bb_w1=(const float*)d_in[7],  *bb_b1=(const float*)d_in[8];
    const float* bb_w2=(const float*)d_in[9],  *bb_b2=(const float*)d_in[10];
    const float* bb_wf=(const float*)d_in[11], *bb_bf=(const float*)d_in[12];
    const float* cl_w1=(const float*)d_in[13], *cl_b1=(const float*)d_in[14];
    const float* cl_w2=(const float*)d_in[15], *cl_b2=(const float*)d_in[16];
    const float* cl_wf=(const float*)d_in[17], *cl_bf=(const float*)d_in[18];
    float* out = (float*)d_out;
    char* ws = (char*)d_ws;

    float* scores=(float*)(ws + 0);
    float* tA    =(float*)(ws + (2u<<20));
    float* mask  =(float*)(ws + (8u<<20));
    float* supp  =(float*)(ws + (10u<<20));
    float* ssb   =(float*)(ws + (12u<<20));
    float* lv    =(float*)(ws + (14u<<20));
    int*   li    =(int*)  (ws + (14u<<20) + (512u<<10));
    float* tv    =(float*)(ws + (15u<<20));
    int*   ti    =(int*)  (ws + (15u<<20) + 4096);
    int*   cnt   =(int*)  (ws + (15u<<20) + 8192);
    u16*   whi1  =(u16*)  (ws + (15u<<20) + 16384);
    u16*   wlo1  =(u16*)  (ws + (15u<<20) + (512u<<10));
    u16*   whi2  =(u16*)  (ws + (16u<<20));
    u16*   wlo2  =(u16*)  (ws + (17u<<20));
    u16*   nbhi  =(u16*)  (ws + (18u<<20));
    u16*   nblo  =(u16*)  (ws + (51u<<20));
    u16*   h1hi  =(u16*)  (ws + (84u<<20));

    const size_t plane_u16 = (size_t)64*66*128;
    const size_t plane2_b  = plane_u16*2*2;
    const size_t fixedb = 84u<<20;
    int Tz = 4;
    if      (ws_size >= fixedb + 66*plane2_b) Tz = 64;
    else if (ws_size >= fixedb + 34*plane2_b) Tz = 32;
    else if (ws_size >= fixedb + 18*plane2_b) Tz = 16;
    else if (ws_size >= fixedb + 10*plane2_b) Tz = 8;
    const int nplanes = Tz + 2;
    u16* h1lo = h1hi + (size_t)nplanes*plane_u16;

    init_k<<<1, 64, 0, stream>>>(cnt);
    repack1b_k<<<(27*128*64 +255)/256, 256, 0, stream>>>(ce_w1, whi1, wlo1);
    repack2_k<<<(27*128*128+255)/256, 256, 0, stream>>>(ce_w2, whi2, wlo2);

    for (int b=0; b<NB; ++b){
        const float* inb = neck + (size_t)b*CIN*G3;
        float* scb = scores + (size_t)b*G3;
        nbconv_k<<<4096, 256, 0, stream>>>(inb, nbhi, nblo);
        for (int z0=0; z0<Gd; z0+=Tz){
            conv1_mfma<<<64*(nplanes/2), 256, 0, stream>>>(nbhi, nblo, whi1, wlo1, ce_b1, h1hi, h1lo, z0);
            conv2_mfma<<<64*(Tz/2),      256, 0, stream>>>(h1hi, h1lo, whi2, wlo2, ce_b2, ce_wf, ce_bf, scb, z0);
        }
    }

    const int n = NB*G3, nb = n/256;
    // simple_nms3d: pool3d = pool_xy + fused z-op
    pool_xy_k<<<NB*64,256,0,stream>>>(scores, tA);
    poolz_eq_k<<<nb,256,0,stream>>>(tA, scores, mask);
    for (int it=0; it<2; ++it){
        pool_xy_k<<<NB*64,256,0,stream>>>(mask, tA);
        poolz_supp_k<<<nb,256,0,stream>>>(tA, scores, supp, ssb);
        pool_xy_k<<<NB*64,256,0,stream>>>(ssb, tA);
        poolz_upd_k<<<nb,256,0,stream>>>(tA, ssb, supp, mask);
    }

    compact_k<<<nb,256,0,stream>>>(mask, scores, lv, li, cnt);
    topsort_k<<<NB,256,0,stream>>>(lv, li, cnt, tv, ti);
    perdet_k<<<NB*TOPKN,512,0,stream>>>(neck, tv, ti,
        bb_w1,bb_b1,bb_w2,bb_b2,bb_wf,bb_bf,
        cl_w1,cl_b1,cl_w2,cl_b2,cl_wf,cl_bf, out);
}

// Round 6
// 1978.897 us; speedup vs baseline: 4.5674x; 1.0101x over previous
//
#include <hip/hip_runtime.h>
#include <math.h>

#define Gd 64
#define G2 4096
#define G3 262144
#define CIN 64
#define HIDC 128
#define NB 2
#define TOPKN 128
#define NCLASS 34
#define CAPN 65536
#define DET_TH 0.2f

typedef unsigned short u16;
typedef unsigned int u32;
typedef unsigned long long u64;
typedef float f32x16 __attribute__((ext_vector_type(16)));
typedef short s16x8  __attribute__((ext_vector_type(8)));

__device__ __forceinline__ u16 f2bf(float x){
    u32 u = __float_as_uint(x);
    u32 r = u + 0x7fffu + ((u>>16)&1u);
    return (u16)(r>>16);
}

// ---------------- weight repack conv1 (bf16 split) -------------------------------
__global__ void repack1b_k(const float* __restrict__ w, u16* __restrict__ whi, u16* __restrict__ wlo){
    int i = blockIdx.x*256 + threadIdx.x;
    if (i >= 27*128*64) return;
    int tap = i >> 13;
    int r   = i & 8191;
    int co  = r >> 6;
    int ci  = r & 63;
    float v = w[((size_t)co*64 + ci)*27 + tap];
    u16 h = f2bf(v);
    float hf = __uint_as_float(((u32)h)<<16);
    u16 l = f2bf(v - hf);
    size_t dst = ((size_t)(tap*4 + (ci>>4))*128 + co)*16 + (ci&15);
    whi[dst] = h; wlo[dst] = l;
}

// ---------------- weight repack conv2 (bf16 split) -------------------------------
__global__ void repack2_k(const float* __restrict__ w, u16* __restrict__ whi, u16* __restrict__ wlo){
    int i = blockIdx.x*256 + threadIdx.x;
    if (i >= 27*128*128) return;
    int tap = i >> 14;
    int r   = i & 16383;
    int co  = r >> 7;
    int ci  = r & 127;
    float v = w[((size_t)co*128 + ci)*27 + tap];
    u16 h = f2bf(v);
    float hf = __uint_as_float(((u32)h)<<16);
    u16 l = f2bf(v - hf);
    size_t dst = ((size_t)(tap*8 + (ci>>4))*128 + co)*16 + (ci&15);
    whi[dst] = h; wlo[dst] = l;
}

// ---------------- neck -> channel-last bf16 hi/lo --------------------------------
__global__ void __launch_bounds__(256) nbconv_k(const float* __restrict__ in,
                                                u16* __restrict__ nhi, u16* __restrict__ nlo){
    const int zy = blockIdx.x;
    const int t  = threadIdx.x;
    __shared__ u16 shi[64][68];
    __shared__ u16 slo[64][68];
    const int x = t & 63, wv = t >> 6;
    const float* src = in + (size_t)zy*64;
    #pragma unroll
    for (int r=0;r<16;++r){
        int ci = wv*16 + r;
        float v = src[(size_t)ci*G3 + x];
        u16 h = f2bf(v);
        float hf = __uint_as_float(((u32)h)<<16);
        shi[x][ci]=h; slo[x][ci]=f2bf(v-hf);
    }
    __syncthreads();
    const size_t obase = (size_t)zy*66*64;
    for (int e=t; e<64*32; e+=256){
        int xx=e>>5, cp=e&31;
        *(u32*)(nhi + obase + (size_t)(xx+1)*64 + 2*cp) = *(const u32*)&shi[xx][2*cp];
        *(u32*)(nlo + obase + (size_t)(xx+1)*64 + 2*cp) = *(const u32*)&slo[xx][2*cp];
    }
    if (t < 64){
        int px = (t<32)?0:65; int cp=t&31;
        *(u32*)(nhi + obase + (size_t)px*64 + 2*cp) = 0u;
        *(u32*)(nlo + obase + (size_t)px*64 + 2*cp) = 0u;
    }
}

// 16 rows (4z x 4y) x 66 x x 2 gg-halves, per array
#define CV_UNITS (16*66*2)   // 2112

// XCD-aware decode: xcd = b&7 owns yt band [xcd*4, xcd*4+4), sweeps zt ascending.
__device__ __forceinline__ void xcd_decode4(int b, int& yt, int& zt){
    int xcd = b & 7, j = b >> 3;
    yt = xcd*4 + (j & 3);
    zt = j >> 2;
}

// ---------------- conv1 (MFMA bf16x3, mt=4): nb(64ci) -> h1(128co) ---------------
// Block: 2 h1-planes x 2 y x 64 x, 4 waves = (sz,sy); each wave all 128 co.
__global__ void __launch_bounds__(256,2) conv1_mfma(
    const u16* __restrict__ nhi, const u16* __restrict__ nlo,
    const u16* __restrict__ whi, const u16* __restrict__ wlo,
    const float* __restrict__ b1,
    u16* __restrict__ h1hi, u16* __restrict__ h1lo, int z0)
{
    int yt, zt; xcd_decode4(blockIdx.x, yt, zt);
    const int t  = threadIdx.x;
    const int lane = t & 63;
    const int w  = t >> 6;
    const int sz = w >> 1;
    const int sy = w & 1;
    const int n  = lane & 31;
    const int g  = lane >> 5;

    __shared__ uint4 sthi[CV_UNITS];
    __shared__ uint4 stlo[CV_UNITS];

    f32x16 acc[4][2];
    #pragma unroll
    for (int a=0;a<4;++a)
        #pragma unroll
        for (int b2_=0;b2_<2;++b2_)
            #pragma unroll
            for (int r=0;r<16;++r) acc[a][b2_][r]=0.f;

    const int aoff_u4 = n*2 + g;

    for (int c=0; c<4; ++c){
        __syncthreads();
        for (int u=t; u<CV_UNITS; u+=256){
            int row = u/132, rem = u-row*132;
            int x = rem>>1, gg = rem&1;
            int zr = row>>2, yr = row&3;
            int zin = z0 - 2 + 2*zt + zr;
            int y = 2*yt - 1 + yr;
            int pu = (row*66 + x)*2 + (gg ^ ((x>>2)&1));
            uint4 vh; vh.x=vh.y=vh.z=vh.w=0u;
            uint4 vl; vl.x=vl.y=vl.z=vl.w=0u;
            if ((unsigned)y < 64u && (unsigned)zin < 64u){
                size_t off = (((size_t)zin*64 + y)*66 + x)*64 + c*16 + gg*8;
                vh = *(const uint4*)(nhi + off);
                vl = *(const uint4*)(nlo + off);
            }
            sthi[pu]=vh; stlo[pu]=vl;
        }
        __syncthreads();
        for (int tap=0; tap<27; ++tap){
            int dz = tap/9, r9 = tap-dz*9;
            int dy = r9/3, dx = r9-dy*3;
            const uint4* wbh = (const uint4*)whi + (size_t)(tap*4+c)*256 + aoff_u4;
            const uint4* wbl = (const uint4*)wlo + (size_t)(tap*4+c)*256 + aoff_u4;
            s16x8 ah[4], al[4];
            #pragma unroll
            for (int mt=0; mt<4; ++mt){
                uint4 th = wbh[mt*64];
                uint4 tl = wbl[mt*64];
                ah[mt] = *(const s16x8*)&th;
                al[mt] = *(const s16x8*)&tl;
            }
            int rowb = ((sz+dz)*4 + (sy+dy))*66;
            #pragma unroll
            for (int j=0;j<2;++j){
                int xpos = j*32 + n + dx;
                int pu = (rowb + xpos)*2 + (g ^ ((xpos>>2)&1));
                uint4 bhq = sthi[pu], blq = stlo[pu];
                s16x8 bh = *(const s16x8*)&bhq;
                s16x8 bl = *(const s16x8*)&blq;
                #pragma unroll
                for (int mt=0; mt<4; ++mt){
                    acc[mt][j] = __builtin_amdgcn_mfma_f32_32x32x16_bf16(al[mt], bh, acc[mt][j],0,0,0);
                    acc[mt][j] = __builtin_amdgcn_mfma_f32_32x32x16_bf16(ah[mt], bl, acc[mt][j],0,0,0);
                    acc[mt][j] = __builtin_amdgcn_mfma_f32_32x32x16_bf16(ah[mt], bh, acc[mt][j],0,0,0);
                }
            }
        }
    }

    // epilogue: bias+relu+split -> h1 channel-last rows for (p, y) of this wave
    const int p = 2*zt + sz;
    const int zglob = z0 - 1 + p;
    const int yo = 2*yt + sy;
    const size_t rowbase = ((size_t)p*64 + yo)*66;
    {   // x pads: x=0 and x=65, 128 co each (2 co per lane as u32)
        size_t pb0 = (rowbase +  0)*128 + 2*lane;
        size_t pb1 = (rowbase + 65)*128 + 2*lane;
        *(u32*)(h1hi + pb0) = 0u; *(u32*)(h1lo + pb0) = 0u;
        *(u32*)(h1hi + pb1) = 0u; *(u32*)(h1lo + pb1) = 0u;
    }
    const bool zok = ((unsigned)zglob < 64u);
    #pragma unroll
    for (int mt=0;mt<4;++mt){
        float bvals[16];
        #pragma unroll
        for (int r=0;r<16;++r)
            bvals[r] = b1[mt*32 + (r&3) + 8*(r>>2) + 4*g];
        #pragma unroll
        for (int j=0;j<2;++j){
            size_t base = (rowbase + j*32 + n + 1)*128 + mt*32;
            u16 hs[16], ls[16];
            #pragma unroll
            for (int r=0;r<16;++r){
                float v = acc[mt][j][r] + bvals[r];
                v = (zok && v>0.f) ? v : 0.f;
                u16 h = f2bf(v);
                float hf = __uint_as_float(((u32)h)<<16);
                hs[r]=h; ls[r]=f2bf(v-hf);
            }
            #pragma unroll
            for (int q=0;q<4;++q){
                size_t addr = base + q*8 + 4*g;
                uint2 sh, sl;
                sh.x = (u32)hs[4*q]   | ((u32)hs[4*q+1]<<16);
                sh.y = (u32)hs[4*q+2] | ((u32)hs[4*q+3]<<16);
                sl.x = (u32)ls[4*q]   | ((u32)ls[4*q+1]<<16);
                sl.y = (u32)ls[4*q+2] | ((u32)ls[4*q+3]<<16);
                *(uint2*)(h1hi + addr) = sh;
                *(uint2*)(h1lo + addr) = sl;
            }
        }
    }
}

// ---------------- conv2 (MFMA bf16x3, mt=4) fused wf-dot + sigmoid -> scores -----
__global__ void __launch_bounds__(256,2) conv2_mfma(
    const u16* __restrict__ h1hi, const u16* __restrict__ h1lo,
    const u16* __restrict__ whi,  const u16* __restrict__ wlo,
    const float* __restrict__ b2, const float* __restrict__ wf,
    const float* __restrict__ bf, float* __restrict__ scores, int z0)
{
    int yt, zt; xcd_decode4(blockIdx.x, yt, zt);
    const int t  = threadIdx.x;
    const int lane = t & 63;
    const int w  = t >> 6;
    const int sz = w >> 1;
    const int sy = w & 1;
    const int n  = lane & 31;
    const int g  = lane >> 5;

    __shared__ uint4 sthi[CV_UNITS];
    __shared__ uint4 stlo[CV_UNITS];

    f32x16 acc[4][2];
    #pragma unroll
    for (int a=0;a<4;++a)
        #pragma unroll
        for (int b2_=0;b2_<2;++b2_)
            #pragma unroll
            for (int r=0;r<16;++r) acc[a][b2_][r]=0.f;

    const int aoff_u4 = n*2 + g;

    for (int c=0; c<8; ++c){
        __syncthreads();
        for (int u=t; u<CV_UNITS; u+=256){
            int row = u/132, rem = u-row*132;
            int x = rem>>1, gg = rem&1;
            int zr = row>>2, yr = row&3;
            int p = 2*zt + zr;
            int y = 2*yt - 1 + yr;
            int pu = (row*66 + x)*2 + (gg ^ ((x>>2)&1));
            uint4 vh; vh.x=vh.y=vh.z=vh.w=0u;
            uint4 vl; vl.x=vl.y=vl.z=vl.w=0u;
            if ((unsigned)y < 64u){
                size_t off = (((size_t)p*64 + y)*66 + x)*128 + c*16 + gg*8;
                vh = *(const uint4*)(h1hi + off);
                vl = *(const uint4*)(h1lo + off);
            }
            sthi[pu]=vh; stlo[pu]=vl;
        }
        __syncthreads();
        for (int tap=0; tap<27; ++tap){
            int dz = tap/9, r9 = tap-dz*9;
            int dy = r9/3, dx = r9-dy*3;
            const uint4* wbh = (const uint4*)whi + (size_t)(tap*8+c)*256 + aoff_u4;
            const uint4* wbl = (const uint4*)wlo + (size_t)(tap*8+c)*256 + aoff_u4;
            s16x8 ah[4], al[4];
            #pragma unroll
            for (int mt=0; mt<4; ++mt){
                uint4 th = wbh[mt*64];
                uint4 tl = wbl[mt*64];
                ah[mt] = *(const s16x8*)&th;
                al[mt] = *(const s16x8*)&tl;
            }
            int rowb = ((sz+dz)*4 + (sy+dy))*66;
            #pragma unroll
            for (int j=0;j<2;++j){
                int xpos = j*32 + n + dx;
                int pu = (rowb + xpos)*2 + (g ^ ((xpos>>2)&1));
                uint4 bhq = sthi[pu], blq = stlo[pu];
                s16x8 bh = *(const s16x8*)&bhq;
                s16x8 bl = *(const s16x8*)&blq;
                #pragma unroll
                for (int mt=0; mt<4; ++mt){
                    acc[mt][j] = __builtin_amdgcn_mfma_f32_32x32x16_bf16(al[mt], bh, acc[mt][j],0,0,0);
                    acc[mt][j] = __builtin_amdgcn_mfma_f32_32x32x16_bf16(ah[mt], bl, acc[mt][j],0,0,0);
                    acc[mt][j] = __builtin_amdgcn_mfma_f32_32x32x16_bf16(ah[mt], bh, acc[mt][j],0,0,0);
                }
            }
        }
    }
    // epilogue: relu(acc+b2) . wf over all 128 co (within wave), + g-half via shfl
    float part[2] = {0.f, 0.f};
    #pragma unroll
    for (int mt=0;mt<4;++mt){
        #pragma unroll
        for (int r=0;r<16;++r){
            int co = mt*32 + (r&3) + 8*(r>>2) + 4*g;
            float b2v = b2[co], wfv = wf[co];
            #pragma unroll
            for (int j=0;j<2;++j){
                float v = acc[mt][j][r] + b2v;
                v = v>0.f?v:0.f;
                part[j] = fmaf(v, wfv, part[j]);
            }
        }
    }
    const int z = z0 + 2*zt + sz;
    const int yo = 2*yt + sy;
    float bfv = bf[0];
    #pragma unroll
    for (int j=0;j<2;++j){
        float tot = part[j] + __shfl_xor(part[j], 32);
        if (g==0)
            scores[((size_t)z*64 + yo)*64 + j*32 + n] = 1.f/(1.f+expf(-(tot+bfv)));
    }
}

// ---------------- fused x+y 5-tap max pool over one z-plane ----------------------
__global__ void __launch_bounds__(256) pool_xy_k(const float* __restrict__ in, float* __restrict__ out){
    const int plane = blockIdx.x;        // 0..NB*64-1
    __shared__ float sp[64][65];
    const float* src = in + (size_t)plane*G2;
    const int t = threadIdx.x;
    for (int e=t; e<4096; e+=256){
        int y=e>>6, x=e&63;
        float v = src[e];
        if (x>=1)  v=fmaxf(v, src[e-1]);
        if (x>=2)  v=fmaxf(v, src[e-2]);
        if (x<=62) v=fmaxf(v, src[e+1]);
        if (x<=61) v=fmaxf(v, src[e+2]);
        sp[y][x]=v;
    }
    __syncthreads();
    float* dst = out + (size_t)plane*G2;
    for (int e=t; e<4096; e+=256){
        int y=e>>6, x=e&63;
        float v = sp[y][x];
        if (y>=1)  v=fmaxf(v, sp[y-1][x]);
        if (y>=2)  v=fmaxf(v, sp[y-2][x]);
        if (y<=62) v=fmaxf(v, sp[y+1][x]);
        if (y<=61) v=fmaxf(v, sp[y+2][x]);
        dst[e]=v;
    }
}

__device__ __forceinline__ float zpool5(const float* __restrict__ a, int i){
    int p = (i >> 12) & 63;
    float v = a[i];
    if (p >= 1)  v = fmaxf(v, a[i - 4096]);
    if (p >= 2)  v = fmaxf(v, a[i - 8192]);
    if (p <= 62) v = fmaxf(v, a[i + 4096]);
    if (p <= 61) v = fmaxf(v, a[i + 8192]);
    return v;
}

// mask = (scores == pool3d(scores))
__global__ void poolz_eq_k(const float* __restrict__ tA, const float* __restrict__ scores,
                           float* __restrict__ mask){
    int i = blockIdx.x*256 + threadIdx.x;
    if (i >= NB*G3) return;
    mask[i] = (scores[i] == zpool5(tA, i)) ? 1.f : 0.f;
}
// supp = pool3d(mask) > 0 ; ss = supp?0:scores
__global__ void poolz_supp_k(const float* __restrict__ tA, const float* __restrict__ scores,
                             float* __restrict__ supp, float* __restrict__ ss){
    int i = blockIdx.x*256 + threadIdx.x;
    if (i >= NB*G3) return;
    bool sp = zpool5(tA, i) > 0.f;
    supp[i] = sp ? 1.f : 0.f;
    ss[i]   = sp ? 0.f : scores[i];
}
// mask |= (ss == pool3d(ss)) & ~supp
__global__ void poolz_upd_k(const float* __restrict__ tA, const float* __restrict__ ss,
                            const float* __restrict__ supp, float* __restrict__ mask){
    int i = blockIdx.x*256 + threadIdx.x;
    if (i >= NB*G3) return;
    bool nm = (ss[i] == zpool5(tA, i)) && (supp[i] == 0.f);
    mask[i] = (mask[i] != 0.f || nm) ? 1.f : 0.f;
}

__global__ void init_k(int* cnt){ if (threadIdx.x < NB) cnt[threadIdx.x]=0; }

// compact: only candidates that can produce valid rows (score > DET_TH)
__global__ void compact_k(const float* __restrict__ mask, const float* __restrict__ s,
                          float* __restrict__ lv, int* __restrict__ li, int* __restrict__ cnt){
    int i = blockIdx.x*256 + threadIdx.x;
    if (i >= NB*G3) return;
    if (mask[i]!=0.f && s[i] > DET_TH){
        int b = i >> 18;
        int pos = atomicAdd(&cnt[b],1);
        if (pos < CAPN){
            lv[(size_t)b*CAPN+pos] = s[i];
            li[(size_t)b*CAPN+pos] = i & (G3-1);
        }
    }
}

// ---------------- top-k via bitonic sort of packed (score,~idx) keys -------------
__device__ __forceinline__ void bitonic2048_desc(u64* sk, int t){
    for (int k=2; k<=2048; k<<=1){
        for (int j=k>>1; j>0; j>>=1){
            #pragma unroll 4
            for (int i=t; i<2048; i+=256){
                int x = i ^ j;
                if (x > i){
                    bool dirDesc = ((i & k) == 0);
                    u64 a = sk[i], b = sk[x];
                    bool sw = dirDesc ? (a < b) : (a > b);
                    if (sw){ sk[i]=b; sk[x]=a; }
                }
            }
            __syncthreads();
        }
    }
}

__global__ void __launch_bounds__(256) topsort_k(const float* __restrict__ lv, const int* __restrict__ li,
                        const int* __restrict__ cnt, float* __restrict__ tv, int* __restrict__ ti){
    const int b = blockIdx.x;
    const int t = threadIdx.x;
    __shared__ u64 sk[2048];
    int n = cnt[b]; if (n > CAPN) n = CAPN;
    const float* Lv = lv + (size_t)b*CAPN;
    const int*   Li = li + (size_t)b*CAPN;

    for (int e=t; e<2048; e+=256){
        u64 key = 0ull;
        if (e < n)
            key = ((u64)__float_as_uint(Lv[e])<<32) | (u32)(~Li[e]);
        sk[e] = key;
    }
    int processed = n < 2048 ? n : 2048;
    __syncthreads();
    bitonic2048_desc(sk, t);
    while (processed < n){
        int chunk = n - processed; if (chunk > 1920) chunk = 1920;
        for (int e=t; e<1920; e+=256){
            u64 key = 0ull;
            if (e < chunk)
                key = ((u64)__float_as_uint(Lv[processed+e])<<32) | (u32)(~Li[processed+e]);
            sk[128+e] = key;
        }
        processed += chunk;
        __syncthreads();
        bitonic2048_desc(sk, t);
    }
    if (t < TOPKN){
        u64 key = sk[t];
        if (key){
            tv[b*TOPKN+t] = __uint_as_float((u32)(key>>32));
            ti[b*TOPKN+t] = (int)(~(u32)key);
        } else {
            tv[b*TOPKN+t] = 0.f;
            ti[b*TOPKN+t] = 0;
        }
    }
}

// ---------------- per-detection bbox+clas heads + decode --------------------------
__global__ void __launch_bounds__(512) perdet_k(
    const float* __restrict__ neck,
    const float* __restrict__ tv, const int* __restrict__ ti,
    const float* __restrict__ bw1, const float* __restrict__ bb1,
    const float* __restrict__ bw2, const float* __restrict__ bb2,
    const float* __restrict__ bwf, const float* __restrict__ bbf,
    const float* __restrict__ lw1, const float* __restrict__ lb1,
    const float* __restrict__ lw2, const float* __restrict__ lb2,
    const float* __restrict__ lwf, const float* __restrict__ lbf,
    float* __restrict__ out)
{
    const int blk = blockIdx.x;
    const int b = blk >> 7, r = blk & 127;
    const int t = threadIdx.x;
    float score = tv[b*TOPKN + r];
    int   idx   = ti[b*TOPKN + r];
    float* orow = out + ((size_t)b*TOPKN + r)*43;
    if (!(score > DET_TH)){
        if (t < 43) orow[t] = 0.f;
        return;
    }
    const int iz = idx >> 12, iy = (idx>>6)&63, ix = idx&63;

    __shared__ float pin[CIN][125];
    __shared__ float h1s[27][HIDC];
    __shared__ float h2s[HIDC];
    __shared__ float raws[7+NCLASS];

    const float* inb = neck + (size_t)b*CIN*G3;
    for (int e=t; e<CIN*125; e+=512){
        int ci=e/125, q=e-ci*125;
        int pz=q/25, py=(q/5)%5, px=q%5;
        int gz=iz-2+pz, gy=iy-2+py, gx=ix-2+px;
        float v=0.f;
        if ((unsigned)gz<64u && (unsigned)gy<64u && (unsigned)gx<64u)
            v = inb[(size_t)ci*G3 + (size_t)gz*G2 + gy*Gd + gx];
        pin[ci][q]=v;
    }
    __syncthreads();

    for (int head=0; head<2; ++head){
        const float* w1 = head? lw1 : bw1;
        const float* b1 = head? lb1 : bb1;
        const float* w2 = head? lw2 : bw2;
        const float* b2 = head? lb2 : bb2;
        const float* wf = head? lwf : bwf;
        const float* bf = head? lbf : bbf;
        const int fdim  = head? NCLASS : 7;

        for (int e=t; e<27*HIDC; e+=512){
            int co = e & 127, pos = e >> 7;
            int pdz=pos/9, pdy=(pos/3)%3, pdx=pos%3;
            int gz=iz-1+pdz, gy=iy-1+pdy, gx=ix-1+pdx;
            float acc = 0.f;
            if ((unsigned)gz<64u && (unsigned)gy<64u && (unsigned)gx<64u){
                acc = b1[co];
                const float* wco = w1 + (size_t)co*CIN*27;
                for (int ci=0; ci<CIN; ++ci){
                    const float* pr = pin[ci];
                    const float* wr = wco + ci*27;
                    #pragma unroll
                    for (int tz=0;tz<3;++tz)
                        #pragma unroll
                        for (int ty=0;ty<3;++ty)
                            #pragma unroll
                            for (int tx=0;tx<3;++tx)
                                acc = fmaf(pr[(pdz+tz)*25+(pdy+ty)*5+(pdx+tx)],
                                           wr[(tz*3+ty)*3+tx], acc);
                }
                acc = acc>0.f ? acc : 0.f;
            }
            h1s[pos][co]=acc;
        }
        __syncthreads();

        if (t < HIDC){
            float acc = b2[t];
            const float* wco = w2 + (size_t)t*HIDC*27;
            for (int pos=0; pos<27; ++pos){
                const float* hr = h1s[pos];
                for (int ci=0; ci<HIDC; ++ci)
                    acc = fmaf(hr[ci], wco[ci*27+pos], acc);
            }
            h2s[t] = acc>0.f ? acc : 0.f;
        }
        __syncthreads();

        if (t < fdim){
            float acc = bf[t];
            const float* wr = wf + t*HIDC;
            for (int ci=0; ci<HIDC; ++ci) acc = fmaf(h2s[ci], wr[ci], acc);
            raws[(head?7:0)+t] = acc;
        }
        __syncthreads();
    }

    if (t==0){
        const float vx = (float)(6.4/64.0);
        float cx = -3.2f + ((float)ix + 0.5f)*vx;
        float cy = -3.2f + ((float)iy + 0.5f)*vx;
        float cz = -3.2f + ((float)iz + 0.5f)*vx;
        float sx = 5.9f*(1.f/(1.f+expf(-raws[0]))) + 0.1f;
        float sy = 5.9f*(1.f/(1.f+expf(-raws[1]))) + 0.1f;
        float sz = 5.9f*(1.f/(1.f+expf(-raws[2]))) + 0.1f;
        float ox = 0.2f*tanhf(raws[3]);
        float oy = 0.2f*tanhf(raws[4]);
        float oz = 0.2f*tanhf(raws[5]);
        float yw = 1.6f*tanhf(raws[6]);
        orow[0]=cx+ox; orow[1]=cy+oy; orow[2]=cz+oz;
        orow[3]=sx; orow[4]=sy; orow[5]=sz;
        orow[6]=yw; orow[7]=score; orow[8]=1.f;
        float mx = raws[7];
        #pragma unroll
        for (int i=1;i<NCLASS;++i) mx = fmaxf(mx, raws[7+i]);
        float ev[NCLASS]; float sum=0.f;
        #pragma unroll
        for (int i=0;i<NCLASS;++i){ ev[i]=expf(raws[7+i]-mx); sum+=ev[i]; }
        float inv = 1.f/sum;
        #pragma unroll
        for (int i=0;i<NCLASS;++i) orow[9+i] = ev[i]*inv;
    }
}

extern "C" void kernel_launch(void* const* d_in, const int* in_sizes, int n_in,
                              void* d_out, int out_size, void* d_ws, size_t ws_size,
                              hipStream_t stream)
{
    (void)in_sizes; (void)n_in; (void)out_size;
    const float* neck = (const float*)d_in[0];
    const float* ce_w1=(const float*)d_in[1],  *ce_b1=(const float*)d_in[2];
    const float* ce_w2=(const float*)d_in[3],  *ce_b2=(const float*)d_in[4];
    const float* ce_wf=(const float*)d_in[5],  *ce_bf=(const float*)d_in[6];
    const float* bb_w1=(const float*)d_in[7],  *bb_b1=(const float*)d_in[8];
    const float* bb_w2=(const float*)d_in[9],  *bb_b2=(const float*)d_in[10];
    const float* bb_wf=(const float*)d_in[11], *bb_bf=(const float*)d_in[12];
    const float* cl_w1=(const float*)d_in[13], *cl_b1=(const float*)d_in[14];
    const float* cl_w2=(const float*)d_in[15], *cl_b2=(const float*)d_in[16];
    const float* cl_wf=(const float*)d_in[17], *cl_bf=(const float*)d_in[18];
    float* out = (float*)d_out;
    char* ws = (char*)d_ws;

    float* scores=(float*)(ws + 0);
    float* tA    =(float*)(ws + (2u<<20));
    float* mask  =(float*)(ws + (8u<<20));
    float* supp  =(float*)(ws + (10u<<20));
    float* ssb   =(float*)(ws + (12u<<20));
    float* lv    =(float*)(ws + (14u<<20));
    int*   li    =(int*)  (ws + (14u<<20) + (512u<<10));
    float* tv    =(float*)(ws + (15u<<20));
    int*   ti    =(int*)  (ws + (15u<<20) + 4096);
    int*   cnt   =(int*)  (ws + (15u<<20) + 8192);
    u16*   whi1  =(u16*)  (ws + (15u<<20) + 16384);
    u16*   wlo1  =(u16*)  (ws + (15u<<20) + (512u<<10));
    u16*   whi2  =(u16*)  (ws + (16u<<20));
    u16*   wlo2  =(u16*)  (ws + (17u<<20));
    u16*   nbhi  =(u16*)  (ws + (18u<<20));
    u16*   nblo  =(u16*)  (ws + (51u<<20));
    u16*   h1hi  =(u16*)  (ws + (84u<<20));

    const size_t plane_u16 = (size_t)64*66*128;
    const size_t plane2_b  = plane_u16*2*2;
    const size_t fixedb = 84u<<20;
    int Tz = 4;
    if      (ws_size >= fixedb + 66*plane2_b) Tz = 64;
    else if (ws_size >= fixedb + 34*plane2_b) Tz = 32;
    else if (ws_size >= fixedb + 18*plane2_b) Tz = 16;
    else if (ws_size >= fixedb + 10*plane2_b) Tz = 8;
    const int nplanes = Tz + 2;
    u16* h1lo = h1hi + (size_t)nplanes*plane_u16;

    init_k<<<1, 64, 0, stream>>>(cnt);
    repack1b_k<<<(27*128*64 +255)/256, 256, 0, stream>>>(ce_w1, whi1, wlo1);
    repack2_k<<<(27*128*128+255)/256, 256, 0, stream>>>(ce_w2, whi2, wlo2);

    for (int b=0; b<NB; ++b){
        const float* inb = neck + (size_t)b*CIN*G3;
        float* scb = scores + (size_t)b*G3;
        nbconv_k<<<4096, 256, 0, stream>>>(inb, nbhi, nblo);
        for (int z0=0; z0<Gd; z0+=Tz){
            conv1_mfma<<<32*(nplanes/2), 256, 0, stream>>>(nbhi, nblo, whi1, wlo1, ce_b1, h1hi, h1lo, z0);
            conv2_mfma<<<32*(Tz/2),      256, 0, stream>>>(h1hi, h1lo, whi2, wlo2, ce_b2, ce_wf, ce_bf, scb, z0);
        }
    }

    const int n = NB*G3, nb = n/256;
    // simple_nms3d: pool3d = pool_xy + fused z-op
    pool_xy_k<<<NB*64,256,0,stream>>>(scores, tA);
    poolz_eq_k<<<nb,256,0,stream>>>(tA, scores, mask);
    for (int it=0; it<2; ++it){
        pool_xy_k<<<NB*64,256,0,stream>>>(mask, tA);
        poolz_supp_k<<<nb,256,0,stream>>>(tA, scores, supp, ssb);
        pool_xy_k<<<NB*64,256,0,stream>>>(ssb, tA);
        poolz_upd_k<<<nb,256,0,stream>>>(tA, ssb, supp, mask);
    }

    compact_k<<<nb,256,0,stream>>>(mask, scores, lv, li, cnt);
    topsort_k<<<NB,256,0,stream>>>(lv, li, cnt, tv, ti);
    perdet_k<<<NB*TOPKN,512,0,stream>>>(neck, tv, ti,
        bb_w1,bb_b1,bb_w2,bb_b2,bb_wf,bb_bf,
        cl_w1,cl_b1,cl_w2,cl_b2,cl_wf,cl_bf, out);
}